// Round 10
// baseline (201.498 us; speedup 1.0000x reference)
//
#include <hip/hip_runtime.h>

// HetGNN fused kernel, round 10: 3 waves/SIMD via 768-thread blocks.
// R9: 95us kernel, VALU 54%, MFMA 16%, ~30% idle = exposed chain latency at
// 2 waves/SIMD. This round buys a 3rd wave per SIMD purely with LDS diet:
//  - Eb merged into eP (single buffer M): in it0 eP is dead before mlp7's
//    new-e scatter; it1 loads e to regs before re-scattering eP. Exact.
//  - CBPO dropped from sConst (epilogue s_loads p.bpost directly).
//  - 12 waves x 5120 B act + 96 KB weights + 4096 B consts = 163840 B exactly.
//  - Grid 228 x 768, PPW=3 (8208 pair-slots >= 8192; tail bounds-checked).
//  - waves_per_eu(3): 170-reg budget, 124 used -> no spill expected.

typedef unsigned short u16;
typedef unsigned int   u32;
typedef __attribute__((ext_vector_type(8))) short short8_t;
typedef __attribute__((ext_vector_type(2))) short short2v;
typedef __attribute__((ext_vector_type(4))) float floatx4;

// u16 offsets of each matrix's fragment block inside sW (fi*512 ordering).
#define OFF_W51 0
#define OFF_W61 8192
#define OFF_W71 16384
#define OFF_W52 24576
#define OFF_W53 28672
#define OFF_W62 32768
#define OFF_W63 36864
#define OFF_W72 40960
#define OFF_W73 45056
#define WS_U16  49152

// f32 offsets inside the sConst LDS table (4096 B total).
#define CB51 0
#define CB52 64
#define CB53 128
#define CB61 192
#define CB62 256
#define CB63 320
#define CB71 384
#define CB72 448
#define CB73 512
#define CWPO 576
#define CWPA 704
#define CBPA 768
#define CWPE 832
#define CBPE 960
#define CSZ  1024

#define PW_U16 2560   // per-wave LDS: M (Eb/eP merged) 1024 | T1 1024 | aPb 512

struct Params {
  const float *ap, *ef;
  const float *wpa, *bpa, *wpe, *bpe;
  const float *w51, *b51, *w52, *b52, *w53, *b53;
  const float *w61, *b61, *w62, *b62, *w63, *b63;
  const float *w71, *b71, *w72, *b72, *w73, *b73;
  const float *wpost, *bpost;
  float *out;
  int gtot;
};

__device__ __forceinline__ u16 f2bf(float f) {
  u32 x = __float_as_uint(f);
  return (u16)((x + 0x7fff + ((x >> 16) & 1)) >> 16);  // RNE
}
__device__ __forceinline__ u32 pk2(float a, float b) {
#if __has_builtin(__builtin_amdgcn_cvt_pk_bf16_f32)
  const auto v = __builtin_amdgcn_cvt_pk_bf16_f32(a, b);  // RNE, a in low half
  return __builtin_bit_cast(u32, v);
#else
  return (u32)f2bf(a) | ((u32)f2bf(b) << 16);
#endif
}
__device__ __forceinline__ float blo(u32 v) { return __uint_as_float(v << 16); }
__device__ __forceinline__ float bhi(u32 v) { return __uint_as_float(v & 0xffff0000u); }
// packed int16 max: valid as bf16 max when one side >= 0 (our running vals).
__device__ __forceinline__ u32 pkmax(u32 a, u32 b) {
  const short2v r = __builtin_elementwise_max(__builtin_bit_cast(short2v, a),
                                              __builtin_bit_cast(short2v, b));
  return __builtin_bit_cast(u32, r);
}
__device__ __forceinline__ u32 ror16(u32 x) { return (x >> 16) | (x << 16); }
__device__ __forceinline__ float sel4(int i, float x0, float x1, float x2, float x3) {
  const float lo = (i & 1) ? x1 : x0;
  const float hi = (i & 1) ? x3 : x2;
  return (i & 2) ? hi : lo;
}

__device__ __forceinline__ floatx4 mfma16(short8_t a, short8_t b, floatx4 c) {
  return __builtin_amdgcn_mfma_f32_16x16x32_bf16(a, b, c, 0, 0, 0);
}
__device__ __forceinline__ short8_t ldA(const u16* buf, int l) {
  return *(const short8_t*)(buf + l * 8);
}

template<int TSTRIDE>
__device__ __forceinline__ void layerK64R(floatx4* acc, short8_t a0, short8_t a1,
                                          const u16* B, int l) {
#pragma unroll
  for (int t = 0; t < 4; ++t) {
    const short8_t b0 = *(const short8_t*)(B + (t * TSTRIDE + 0) * 512 + l * 8);
    const short8_t b1 = *(const short8_t*)(B + (t * TSTRIDE + 1) * 512 + l * 8);
    acc[t] = mfma16(a0, b0, acc[t]);
    acc[t] = mfma16(a1, b1, acc[t]);
  }
}

__device__ __forceinline__ void layerK128R(floatx4* acc, short8_t a0, short8_t a1,
                                           short8_t a2, short8_t a3,
                                           const u16* B, int l) {
  short8_t a[4] = {a0, a1, a2, a3};
#pragma unroll
  for (int t = 0; t < 4; ++t)
#pragma unroll
    for (int h = 0; h < 4; ++h)
      acc[t] = mfma16(a[h], *(const short8_t*)(B + (t * 4 + h) * 512 + l * 8), acc[t]);
}

__device__ __forceinline__ void scatter_relu_bf16(u16* dst, const floatx4* acc, int q, int n) {
#pragma unroll
  for (int t = 0; t < 4; ++t) {
    const int kk = (t & 1) * 2 + (n >> 3);
    u16* base = dst + (t >> 1) * 512 + (n & 7);
    const u32 v01 = pk2(fmaxf(acc[t][0], 0.f), fmaxf(acc[t][1], 0.f));
    const u32 v23 = pk2(fmaxf(acc[t][2], 0.f), fmaxf(acc[t][3], 0.f));
    base[(4 * q + 0 + 16 * kk) * 8] = (u16)v01;
    base[(4 * q + 1 + 16 * kk) * 8] = (u16)(v01 >> 16);
    base[(4 * q + 2 + 16 * kk) * 8] = (u16)v23;
    base[(4 * q + 3 + 16 * kk) * 8] = (u16)(v23 >> 16);
  }
}

__device__ __forceinline__ void scatter_bf16(u16* dst, const floatx4* acc, int q, int n) {
#pragma unroll
  for (int t = 0; t < 4; ++t) {
    const int kk = (t & 1) * 2 + (n >> 3);
    u16* base = dst + (t >> 1) * 512 + (n & 7);
    const u32 v01 = pk2(acc[t][0], acc[t][1]);
    const u32 v23 = pk2(acc[t][2], acc[t][3]);
    base[(4 * q + 0 + 16 * kk) * 8] = (u16)v01;
    base[(4 * q + 1 + 16 * kk) * 8] = (u16)(v01 >> 16);
    base[(4 * q + 2 + 16 * kk) * 8] = (u16)v23;
    base[(4 * q + 3 + 16 * kk) * 8] = (u16)(v23 >> 16);
  }
}

__device__ __forceinline__ void scatter_pk(u16* dst, const u32* src, int q, int n) {
#pragma unroll
  for (int t = 0; t < 4; ++t) {
    const int kk = (t & 1) * 2 + (n >> 3);
    u16* base = dst + (t >> 1) * 512 + (n & 7);
#pragma unroll
    for (int half = 0; half < 2; ++half) {
      const u32 v = src[2 * t + half];
      base[(4 * q + 2 * half + 0 + 16 * kk) * 8] = (u16)v;
      base[(4 * q + 2 * half + 1 + 16 * kk) * 8] = (u16)(v >> 16);
    }
  }
}

__device__ __forceinline__ void scatter_aP(u16* dst, const floatx4* acc, int q, int n) {
#pragma unroll
  for (int t = 0; t < 4; ++t) {
    const int kk = (t & 1) * 2 + (n >> 3);
    u16* base = dst + (t >> 1) * 256 + (n & 7);
    const u32 v = pk2(acc[t][0], acc[t][2]);   // rows 4q,4q+2 -> d=2q,2q+1
    base[(2 * q + 0 + 8 * kk) * 8] = (u16)v;
    base[(2 * q + 1 + 8 * kk) * 8] = (u16)(v >> 16);
  }
}

__device__ __forceinline__ void init_accL(floatx4* acc, const float* cb, int n) {
#pragma unroll
  for (int t = 0; t < 4; ++t) {
    const float b = cb[16 * t + n];
    floatx4 v; v[0] = b; v[1] = b; v[2] = b; v[3] = b;
    acc[t] = v;
  }
}

struct frag2 { short8_t f0, f1; };

__device__ __forceinline__ frag2 make_a(float apv, int q, const float* sc) {
  frag2 r;
#pragma unroll
  for (int h = 0; h < 2; ++h) {
    const int fb = 32 * h + 8 * q;
    const float4 wa0 = *(const float4*)(sc + CWPA + fb);
    const float4 wa1 = *(const float4*)(sc + CWPA + fb + 4);
    const float4 ba0 = *(const float4*)(sc + CBPA + fb);
    const float4 ba1 = *(const float4*)(sc + CBPA + fb + 4);
    uint4 pa;
    pa.x = pk2(fmaxf(fmaf(apv, wa0.x, ba0.x), 0.f), fmaxf(fmaf(apv, wa0.y, ba0.y), 0.f));
    pa.y = pk2(fmaxf(fmaf(apv, wa0.z, ba0.z), 0.f), fmaxf(fmaf(apv, wa0.w, ba0.w), 0.f));
    pa.z = pk2(fmaxf(fmaf(apv, wa1.x, ba1.x), 0.f), fmaxf(fmaf(apv, wa1.y, ba1.y), 0.f));
    pa.w = pk2(fmaxf(fmaf(apv, wa1.z, ba1.z), 0.f), fmaxf(fmaf(apv, wa1.w, ba1.w), 0.f));
    if (h == 0) r.f0 = __builtin_bit_cast(short8_t, pa);
    else        r.f1 = __builtin_bit_cast(short8_t, pa);
  }
  return r;
}

#define NBLK 228
#define NWAVE 12
#define PPW  3   // 228 blk * 12 waves * 3 pairs = 8208 slots >= 8192 pairs

__global__ __launch_bounds__(768)
__attribute__((amdgpu_waves_per_eu(3)))
void hetgnn_mfma(Params p) {
  __shared__ __align__(16) u16   sW[WS_U16];            // 96 KB weights
  __shared__ __align__(16) u16   sAct[NWAVE * PW_U16];  // 60 KB: 12 x (M|T1|aPb)
  __shared__ __align__(16) float sConst[CSZ];           // 4 KB
  // total 98304 + 61440 + 4096 = 163840 B (exact LDS fit)

  const int tid  = threadIdx.x;
  const int wave = tid >> 6;
  const int l    = tid & 63;
  const int q    = l >> 4;
  const int n    = l & 15;

  // ---- stage + swizzle weights (f32 global -> bf16 B-frag LDS), 8 frags/wave ----
  {
    const float* mats[9] = {p.w51, p.w61, p.w71, p.w52, p.w53, p.w62, p.w63, p.w72, p.w73};
    for (int i = 0; i < 8; ++i) {
      const int fi = wave * 8 + i;   // wave-uniform, 0..95
      const float* W;
      int t, h;
      if (fi < 48) { W = mats[fi >> 4]; const int loc = fi & 15; t = loc >> 2; h = loc & 3; }
      else { const int j = fi - 48; W = mats[3 + (j >> 3)]; const int loc = j & 7; t = loc >> 1; h = loc & 1; }
      const int nn = 16 * t + (l & 15);
      const int k0 = 32 * h + (l >> 4) * 8;
      float w[8];
#pragma unroll
      for (int j = 0; j < 8; ++j) w[j] = W[(k0 + j) * 64 + nn];
      uint4 o;
      o.x = pk2(w[0], w[1]); o.y = pk2(w[2], w[3]);
      o.z = pk2(w[4], w[5]); o.w = pk2(w[6], w[7]);
      *(uint4*)(sW + fi * 512 + l * 8) = o;
    }
  }
  if (tid < 64) {
    sConst[CB51 + tid] = p.b51[tid];
    sConst[CB52 + tid] = p.b52[tid];
    sConst[CB53 + tid] = p.b53[tid];
    sConst[CB61 + tid] = p.b61[tid];
    sConst[CB62 + tid] = p.b62[tid];
    sConst[CB63 + tid] = p.b63[tid];
    sConst[CB71 + tid] = p.b71[tid];
    sConst[CB72 + tid] = p.b72[tid];
    sConst[CB73 + tid] = p.b73[tid];
    sConst[CWPA + tid] = p.wpa[tid];
    sConst[CBPA + tid] = p.bpa[tid];
    sConst[CBPE + tid] = p.bpe[tid];
  }
  if (tid < 128) {
    sConst[CWPO + tid] = p.wpost[tid];
    sConst[CWPE + tid] = p.wpe[tid];
  }
  __syncthreads();

  u16* M   = sAct + wave * PW_U16;  // merged: eP scratch within an iter; new-e across it0->it1
  u16* T1  = M + 1024;
  u16* aPb = M + 2048;

  const float bpR = p.bpost[0], bpI = p.bpost[1];
  const int wslot = blockIdx.x * NWAVE + wave;

  for (int pi = 0; pi < PPW; ++pi) {
    const int g0 = (wslot * PPW + pi) * 2;   // 2 graphs: g0, g0+1
    if (g0 + 2 > p.gtot) break;

    // ---------------- pre-layer: a-rows and e-rows straight into registers ----------------
    const float apv = p.ap[(g0 + (n >> 3)) * 4 + ((n >> 1) & 3)];
    const frag2 A = make_a(apv, q, sConst);          // persists across both iterations
    short8_t e0, e1;
    {
      const float f0 = p.ef[(g0 + (n >> 3)) * 16 + (n & 7) * 2];
      const float f1 = p.ef[(g0 + (n >> 3)) * 16 + (n & 7) * 2 + 1];
#pragma unroll
      for (int h = 0; h < 2; ++h) {
        const int fb = 32 * h + 8 * q;
        const float4 w00 = *(const float4*)(sConst + CWPE + fb);
        const float4 w01 = *(const float4*)(sConst + CWPE + fb + 4);
        const float4 w10 = *(const float4*)(sConst + CWPE + 64 + fb);
        const float4 w11 = *(const float4*)(sConst + CWPE + 64 + fb + 4);
        const float4 be0 = *(const float4*)(sConst + CBPE + fb);
        const float4 be1 = *(const float4*)(sConst + CBPE + fb + 4);
        uint4 pe;
        pe.x = pk2(fmaxf(fmaf(f0, w00.x, fmaf(f1, w10.x, be0.x)), 0.f),
                   fmaxf(fmaf(f0, w00.y, fmaf(f1, w10.y, be0.y)), 0.f));
        pe.y = pk2(fmaxf(fmaf(f0, w00.z, fmaf(f1, w10.z, be0.z)), 0.f),
                   fmaxf(fmaf(f0, w00.w, fmaf(f1, w10.w, be0.w)), 0.f));
        pe.z = pk2(fmaxf(fmaf(f0, w01.x, fmaf(f1, w11.x, be1.x)), 0.f),
                   fmaxf(fmaf(f0, w01.y, fmaf(f1, w11.y, be1.y)), 0.f));
        pe.w = pk2(fmaxf(fmaf(f0, w01.z, fmaf(f1, w11.z, be1.z)), 0.f),
                   fmaxf(fmaf(f0, w01.w, fmaf(f1, w11.w, be1.w)), 0.f));
        if (h == 0) e0 = __builtin_bit_cast(short8_t, pe);
        else        e1 = __builtin_bit_cast(short8_t, pe);
      }
    }

    // ---- aP = a @ w61[:64]: iteration-invariant, A from regs ----
    {
      floatx4 accA[4];
#pragma unroll
      for (int t = 0; t < 4; ++t) { accA[t][0] = 0.f; accA[t][1] = 0.f; accA[t][2] = 0.f; accA[t][3] = 0.f; }
      layerK64R<4>(accA, A.f0, A.f1, sW + OFF_W61, l);
      scatter_aP(aPb, accA, q, n);
    }

    // ---------------- 2 shared-weight update iterations ----------------
#pragma unroll 1
    for (int it = 0; it < 2; ++it) {
      if (it == 1) { e0 = ldA(M, l); e1 = ldA(M + 512, l); }  // new e from it0

      // ---- mlp5 -> m1 ----
      u32 m1p[8];
      {
        floatx4 acc[4]; init_accL(acc, sConst + CB51, n);
        layerK128R(acc, A.f0, A.f1, e0, e1, sW + OFF_W51, l);
        scatter_relu_bf16(T1, acc, q, n);
        floatx4 acc2[4]; init_accL(acc2, sConst + CB52, n);
        layerK64R<2>(acc2, ldA(T1, l), ldA(T1 + 512, l), sW + OFF_W52, l);
        scatter_relu_bf16(T1, acc2, q, n);
        floatx4 acc3[4]; init_accL(acc3, sConst + CB53, n);
        layerK64R<2>(acc3, ldA(T1, l), ldA(T1 + 512, l), sW + OFF_W53, l);
#pragma unroll
        for (int t = 0; t < 4; ++t) {
          m1p[2 * t + 0] = pk2(acc3[t][0], acc3[t][1]);
          m1p[2 * t + 1] = pk2(acc3[t][2], acc3[t][3]);
        }
      }

      // ---- mlp6 -> m2 (masked running max; h in regs; eP in M) ----
      u32 m2p[8];
#pragma unroll
      for (int i = 0; i < 8; ++i) m2p[i] = 0u;
      {
        floatx4 accE[4];
#pragma unroll
        for (int t = 0; t < 4; ++t) { accE[t][0] = 0.f; accE[t][1] = 0.f; accE[t][2] = 0.f; accE[t][3] = 0.f; }
        layerK64R<4>(accE, e0, e1, sW + OFF_W61 + 2 * 512, l);
        scatter_bf16(M, accE, q, n);   // eP lives in M (dead before new-e write)

        const int d = n >> 1;
#pragma unroll 2
        for (int bp = 0; bp < 4; ++bp) {
          const int re = (n & 8) + bp * 2 + (n & 1);
          short8_t h0, h1;
#pragma unroll
          for (int h = 0; h < 2; ++h) {
            const uint4 av = *(const uint4*)(aPb + h * 256 + (d + 8 * q) * 8);
            const uint4 ev = *(const uint4*)(M + h * 512 + (re + 16 * q) * 8);
            const float4 b0 = *(const float4*)(sConst + CB61 + 32 * h + 8 * q);
            const float4 b1 = *(const float4*)(sConst + CB61 + 32 * h + 8 * q + 4);
            uint4 ph;
            ph.x = pk2(fmaxf(blo(av.x) + blo(ev.x) + b0.x, 0.f),
                       fmaxf(bhi(av.x) + bhi(ev.x) + b0.y, 0.f));
            ph.y = pk2(fmaxf(blo(av.y) + blo(ev.y) + b0.z, 0.f),
                       fmaxf(bhi(av.y) + bhi(ev.y) + b0.w, 0.f));
            ph.z = pk2(fmaxf(blo(av.z) + blo(ev.z) + b1.x, 0.f),
                       fmaxf(bhi(av.z) + bhi(ev.z) + b1.y, 0.f));
            ph.w = pk2(fmaxf(blo(av.w) + blo(ev.w) + b1.z, 0.f),
                       fmaxf(bhi(av.w) + bhi(ev.w) + b1.w, 0.f));
            if (h == 0) h0 = __builtin_bit_cast(short8_t, ph);
            else        h1 = __builtin_bit_cast(short8_t, ph);
          }
          floatx4 acc2[4]; init_accL(acc2, sConst + CB62, n);
          layerK64R<2>(acc2, h0, h1, sW + OFF_W62, l);
          scatter_relu_bf16(T1, acc2, q, n);
          floatx4 acc3[4]; init_accL(acc3, sConst + CB63, n);
          layerK64R<2>(acc3, ldA(T1, l), ldA(T1 + 512, l), sW + OFF_W63, l);
#pragma unroll
          for (int t = 0; t < 4; ++t) {
#pragma unroll
            for (int h = 0; h < 2; ++h) {
              const u32 cand = pk2(acc3[t][2 * h], acc3[t][2 * h + 1]);
              const u32 mx = pkmax(m2p[2 * t + h], cand);
              m2p[2 * t + h] = (((2 * q + h) & 3) != bp) ? mx : m2p[2 * t + h];
            }
          }
        }
      }

      // ---- agg + mlp7 ----
      {
        u32 agp[8];
#pragma unroll
        for (int i = 0; i < 8; ++i) agp[i] = pkmax(ror16(m1p[i]), m2p[i]);
        scatter_pk(T1, agp, q, n);
        floatx4 acc[4]; init_accL(acc, sConst + CB71, n);
        layerK128R(acc, ldA(T1, l), ldA(T1 + 512, l), e0, e1, sW + OFF_W71, l);
        scatter_relu_bf16(T1, acc, q, n);
        floatx4 acc2[4]; init_accL(acc2, sConst + CB72, n);
        layerK64R<2>(acc2, ldA(T1, l), ldA(T1 + 512, l), sW + OFF_W72, l);
        scatter_relu_bf16(T1, acc2, q, n);
        floatx4 acc3[4]; init_accL(acc3, sConst + CB73, n);
        layerK64R<2>(acc3, ldA(T1, l), ldA(T1 + 512, l), sW + OFF_W73, l);

        if (it == 0) {
          scatter_relu_bf16(M, acc3, q, n);   // new e -> M (eP dead now)
        } else {
          // ---- post linear + per-(g,b) L2 row normalization ----
          float prr[4] = {0.f, 0.f, 0.f, 0.f}, pii[4] = {0.f, 0.f, 0.f, 0.f};
#pragma unroll
          for (int t = 0; t < 4; ++t) {
            const float wr = sConst[CWPO + (16 * t + n) * 2];
            const float wi = sConst[CWPO + (16 * t + n) * 2 + 1];
#pragma unroll
            for (int r = 0; r < 4; ++r) {
              const float e = fmaxf(acc3[t][r], 0.f);
              prr[r] = fmaf(e, wr, prr[r]);
              pii[r] = fmaf(e, wi, pii[r]);
            }
          }
#pragma unroll
          for (int r = 0; r < 4; ++r) {
#pragma unroll
            for (int off = 1; off < 16; off <<= 1) {
              prr[r] += __shfl_xor(prr[r], off, 16);
              pii[r] += __shfl_xor(pii[r], off, 16);
            }
            prr[r] += bpR;
            pii[r] += bpI;
          }
          const int r = n >> 1, c = n & 1, rp = r ^ 1;
          const float pr_r  = sel4(r,  prr[0], prr[1], prr[2], prr[3]);
          const float pi_r  = sel4(r,  pii[0], pii[1], pii[2], pii[3]);
          const float pr_rp = sel4(rp, prr[0], prr[1], prr[2], prr[3]);
          const float pi_rp = sel4(rp, pii[0], pii[1], pii[2], pii[3]);
          const float num = c ? pi_r : pr_r;
          const float n2  = pr_r * pr_r + pi_r * pi_r + pr_rp * pr_rp + pi_rp * pi_rp;
          if (n < 8) p.out[g0 * 16 + (4 * q + r) * 2 + c] = num / sqrtf(n2);
        }
      }
    }
  }
}

extern "C" void kernel_launch(void* const* d_in, const int* in_sizes, int n_in,
                              void* d_out, int out_size, void* d_ws, size_t ws_size,
                              hipStream_t stream) {
  Params p;
  p.ap    = (const float*)d_in[0];
  p.ef    = (const float*)d_in[1];
  p.wpa   = (const float*)d_in[2];  p.bpa   = (const float*)d_in[3];
  p.wpe   = (const float*)d_in[4];  p.bpe   = (const float*)d_in[5];
  p.w51   = (const float*)d_in[6];  p.b51   = (const float*)d_in[7];
  p.w52   = (const float*)d_in[8];  p.b52   = (const float*)d_in[9];
  p.w53   = (const float*)d_in[10]; p.b53   = (const float*)d_in[11];
  p.w61   = (const float*)d_in[12]; p.b61   = (const float*)d_in[13];
  p.w62   = (const float*)d_in[14]; p.b62   = (const float*)d_in[15];
  p.w63   = (const float*)d_in[16]; p.b63   = (const float*)d_in[17];
  p.w71   = (const float*)d_in[18]; p.b71   = (const float*)d_in[19];
  p.w72   = (const float*)d_in[20]; p.b72   = (const float*)d_in[21];
  p.w73   = (const float*)d_in[22]; p.b73   = (const float*)d_in[23];
  p.wpost = (const float*)d_in[24]; p.bpost = (const float*)d_in[25];
  p.out   = (float*)d_out;
  p.gtot  = in_sizes[0] / 4;  // G from ap_feat [G,B,1]

  hipLaunchKernelGGL(hetgnn_mfma, dim3(NBLK), dim3(768), 0, stream, p);
}

// Round 11
// 182.911 us; speedup vs baseline: 1.1016x; 1.1016x over previous
//
#include <hip/hip_runtime.h>

// HetGNN fused kernel, round 11: revert to the 2-waves/SIMD no-spill envelope
// (R10's 3rd wave forced VGPR 124->84 and 124 MB spill WRITE; regressed).
// Buy latency hiding with in-wave ILP instead:
//  - bp loop FULLY unrolled with alternating scratch (even bp->T1, odd->T2):
//    four independent 2-layer chains can overlap (R9's shared T1 serialized
//    them via alias-forced DS ordering). T2 funded by merging new-e into the
//    eP buffer M (R10's exact-ordering trick) -- per-wave stays 7168 B.
//  - eP layer (accE+scatter) hoisted ahead of mlp5: hides under mlp5's chain.
//  - mlp5/mlp7 alternate T1/T2 within their chains.
// Block: 512 thr, 8 waves, 2/SIMD; LDS 98304+57344+4096 = 159744 B; PPW=4.

typedef unsigned short u16;
typedef unsigned int   u32;
typedef __attribute__((ext_vector_type(8))) short short8_t;
typedef __attribute__((ext_vector_type(2))) short short2v;
typedef __attribute__((ext_vector_type(4))) float floatx4;

// u16 offsets of each matrix's fragment block inside sW (fi*512 ordering).
#define OFF_W51 0
#define OFF_W61 8192
#define OFF_W71 16384
#define OFF_W52 24576
#define OFF_W53 28672
#define OFF_W62 32768
#define OFF_W63 36864
#define OFF_W72 40960
#define OFF_W73 45056
#define WS_U16  49152

// f32 offsets inside the sConst LDS table (4096 B total).
#define CB51 0
#define CB52 64
#define CB53 128
#define CB61 192
#define CB62 256
#define CB63 320
#define CB71 384
#define CB72 448
#define CB73 512
#define CWPO 576
#define CWPA 704
#define CBPA 768
#define CWPE 832
#define CBPE 960
#define CSZ  1024

#define PW_U16 3584   // per-wave LDS: M 1024 | T1 1024 | T2 1024 | aPb 512

struct Params {
  const float *ap, *ef;
  const float *wpa, *bpa, *wpe, *bpe;
  const float *w51, *b51, *w52, *b52, *w53, *b53;
  const float *w61, *b61, *w62, *b62, *w63, *b63;
  const float *w71, *b71, *w72, *b72, *w73, *b73;
  const float *wpost, *bpost;
  float *out;
  int gtot;
};

__device__ __forceinline__ u16 f2bf(float f) {
  u32 x = __float_as_uint(f);
  return (u16)((x + 0x7fff + ((x >> 16) & 1)) >> 16);  // RNE
}
__device__ __forceinline__ u32 pk2(float a, float b) {
#if __has_builtin(__builtin_amdgcn_cvt_pk_bf16_f32)
  const auto v = __builtin_amdgcn_cvt_pk_bf16_f32(a, b);  // RNE, a in low half
  return __builtin_bit_cast(u32, v);
#else
  return (u32)f2bf(a) | ((u32)f2bf(b) << 16);
#endif
}
__device__ __forceinline__ float blo(u32 v) { return __uint_as_float(v << 16); }
__device__ __forceinline__ float bhi(u32 v) { return __uint_as_float(v & 0xffff0000u); }
// packed int16 max: valid as bf16 max when one side >= 0 (our running vals).
__device__ __forceinline__ u32 pkmax(u32 a, u32 b) {
  const short2v r = __builtin_elementwise_max(__builtin_bit_cast(short2v, a),
                                              __builtin_bit_cast(short2v, b));
  return __builtin_bit_cast(u32, r);
}
__device__ __forceinline__ u32 ror16(u32 x) { return (x >> 16) | (x << 16); }
__device__ __forceinline__ float sel4(int i, float x0, float x1, float x2, float x3) {
  const float lo = (i & 1) ? x1 : x0;
  const float hi = (i & 1) ? x3 : x2;
  return (i & 2) ? hi : lo;
}

__device__ __forceinline__ floatx4 mfma16(short8_t a, short8_t b, floatx4 c) {
  return __builtin_amdgcn_mfma_f32_16x16x32_bf16(a, b, c, 0, 0, 0);
}
__device__ __forceinline__ short8_t ldA(const u16* buf, int l) {
  return *(const short8_t*)(buf + l * 8);
}

template<int TSTRIDE>
__device__ __forceinline__ void layerK64R(floatx4* acc, short8_t a0, short8_t a1,
                                          const u16* B, int l) {
#pragma unroll
  for (int t = 0; t < 4; ++t) {
    const short8_t b0 = *(const short8_t*)(B + (t * TSTRIDE + 0) * 512 + l * 8);
    const short8_t b1 = *(const short8_t*)(B + (t * TSTRIDE + 1) * 512 + l * 8);
    acc[t] = mfma16(a0, b0, acc[t]);
    acc[t] = mfma16(a1, b1, acc[t]);
  }
}

__device__ __forceinline__ void layerK128R(floatx4* acc, short8_t a0, short8_t a1,
                                           short8_t a2, short8_t a3,
                                           const u16* B, int l) {
  short8_t a[4] = {a0, a1, a2, a3};
#pragma unroll
  for (int t = 0; t < 4; ++t)
#pragma unroll
    for (int h = 0; h < 4; ++h)
      acc[t] = mfma16(a[h], *(const short8_t*)(B + (t * 4 + h) * 512 + l * 8), acc[t]);
}

__device__ __forceinline__ void scatter_relu_bf16(u16* dst, const floatx4* acc, int q, int n) {
#pragma unroll
  for (int t = 0; t < 4; ++t) {
    const int kk = (t & 1) * 2 + (n >> 3);
    u16* base = dst + (t >> 1) * 512 + (n & 7);
    const u32 v01 = pk2(fmaxf(acc[t][0], 0.f), fmaxf(acc[t][1], 0.f));
    const u32 v23 = pk2(fmaxf(acc[t][2], 0.f), fmaxf(acc[t][3], 0.f));
    base[(4 * q + 0 + 16 * kk) * 8] = (u16)v01;
    base[(4 * q + 1 + 16 * kk) * 8] = (u16)(v01 >> 16);
    base[(4 * q + 2 + 16 * kk) * 8] = (u16)v23;
    base[(4 * q + 3 + 16 * kk) * 8] = (u16)(v23 >> 16);
  }
}

__device__ __forceinline__ void scatter_bf16(u16* dst, const floatx4* acc, int q, int n) {
#pragma unroll
  for (int t = 0; t < 4; ++t) {
    const int kk = (t & 1) * 2 + (n >> 3);
    u16* base = dst + (t >> 1) * 512 + (n & 7);
    const u32 v01 = pk2(acc[t][0], acc[t][1]);
    const u32 v23 = pk2(acc[t][2], acc[t][3]);
    base[(4 * q + 0 + 16 * kk) * 8] = (u16)v01;
    base[(4 * q + 1 + 16 * kk) * 8] = (u16)(v01 >> 16);
    base[(4 * q + 2 + 16 * kk) * 8] = (u16)v23;
    base[(4 * q + 3 + 16 * kk) * 8] = (u16)(v23 >> 16);
  }
}

__device__ __forceinline__ void scatter_pk(u16* dst, const u32* src, int q, int n) {
#pragma unroll
  for (int t = 0; t < 4; ++t) {
    const int kk = (t & 1) * 2 + (n >> 3);
    u16* base = dst + (t >> 1) * 512 + (n & 7);
#pragma unroll
    for (int half = 0; half < 2; ++half) {
      const u32 v = src[2 * t + half];
      base[(4 * q + 2 * half + 0 + 16 * kk) * 8] = (u16)v;
      base[(4 * q + 2 * half + 1 + 16 * kk) * 8] = (u16)(v >> 16);
    }
  }
}

__device__ __forceinline__ void scatter_aP(u16* dst, const floatx4* acc, int q, int n) {
#pragma unroll
  for (int t = 0; t < 4; ++t) {
    const int kk = (t & 1) * 2 + (n >> 3);
    u16* base = dst + (t >> 1) * 256 + (n & 7);
    const u32 v = pk2(acc[t][0], acc[t][2]);   // rows 4q,4q+2 -> d=2q,2q+1
    base[(2 * q + 0 + 8 * kk) * 8] = (u16)v;
    base[(2 * q + 1 + 8 * kk) * 8] = (u16)(v >> 16);
  }
}

__device__ __forceinline__ void init_accL(floatx4* acc, const float* cb, int n) {
#pragma unroll
  for (int t = 0; t < 4; ++t) {
    const float b = cb[16 * t + n];
    floatx4 v; v[0] = b; v[1] = b; v[2] = b; v[3] = b;
    acc[t] = v;
  }
}

struct frag2 { short8_t f0, f1; };

__device__ __forceinline__ frag2 make_a(float apv, int q, const float* sc) {
  frag2 r;
#pragma unroll
  for (int h = 0; h < 2; ++h) {
    const int fb = 32 * h + 8 * q;
    const float4 wa0 = *(const float4*)(sc + CWPA + fb);
    const float4 wa1 = *(const float4*)(sc + CWPA + fb + 4);
    const float4 ba0 = *(const float4*)(sc + CBPA + fb);
    const float4 ba1 = *(const float4*)(sc + CBPA + fb + 4);
    uint4 pa;
    pa.x = pk2(fmaxf(fmaf(apv, wa0.x, ba0.x), 0.f), fmaxf(fmaf(apv, wa0.y, ba0.y), 0.f));
    pa.y = pk2(fmaxf(fmaf(apv, wa0.z, ba0.z), 0.f), fmaxf(fmaf(apv, wa0.w, ba0.w), 0.f));
    pa.z = pk2(fmaxf(fmaf(apv, wa1.x, ba1.x), 0.f), fmaxf(fmaf(apv, wa1.y, ba1.y), 0.f));
    pa.w = pk2(fmaxf(fmaf(apv, wa1.z, ba1.z), 0.f), fmaxf(fmaf(apv, wa1.w, ba1.w), 0.f));
    if (h == 0) r.f0 = __builtin_bit_cast(short8_t, pa);
    else        r.f1 = __builtin_bit_cast(short8_t, pa);
  }
  return r;
}

#define NBLK 256
#define NWAVE 8
#define PPW  4   // 256 blk * 8 waves * 4 pairs = 8192 pairs = 16384 graphs

__global__ __launch_bounds__(512)
__attribute__((amdgpu_waves_per_eu(2)))
void hetgnn_mfma(Params p) {
  __shared__ __align__(16) u16   sW[WS_U16];            // 96 KB weights
  __shared__ __align__(16) u16   sAct[NWAVE * PW_U16];  // 56 KB: 8 x (M|T1|T2|aPb)
  __shared__ __align__(16) float sConst[CSZ];           // 4 KB
  // total 98304 + 57344 + 4096 = 159744 B

  const int tid  = threadIdx.x;
  const int wave = tid >> 6;
  const int l    = tid & 63;
  const int q    = l >> 4;
  const int n    = l & 15;

  // ---- stage + swizzle weights (f32 global -> bf16 B-frag LDS), 12 frags/wave ----
  {
    const float* mats[9] = {p.w51, p.w61, p.w71, p.w52, p.w53, p.w62, p.w63, p.w72, p.w73};
    for (int i = 0; i < 12; ++i) {
      const int fi = wave * 12 + i;   // wave-uniform, 0..95
      const float* W;
      int t, h;
      if (fi < 48) { W = mats[fi >> 4]; const int loc = fi & 15; t = loc >> 2; h = loc & 3; }
      else { const int j = fi - 48; W = mats[3 + (j >> 3)]; const int loc = j & 7; t = loc >> 1; h = loc & 1; }
      const int nn = 16 * t + (l & 15);
      const int k0 = 32 * h + (l >> 4) * 8;
      float w[8];
#pragma unroll
      for (int j = 0; j < 8; ++j) w[j] = W[(k0 + j) * 64 + nn];
      uint4 o;
      o.x = pk2(w[0], w[1]); o.y = pk2(w[2], w[3]);
      o.z = pk2(w[4], w[5]); o.w = pk2(w[6], w[7]);
      *(uint4*)(sW + fi * 512 + l * 8) = o;
    }
  }
  if (tid < 64) {
    sConst[CB51 + tid] = p.b51[tid];
    sConst[CB52 + tid] = p.b52[tid];
    sConst[CB53 + tid] = p.b53[tid];
    sConst[CB61 + tid] = p.b61[tid];
    sConst[CB62 + tid] = p.b62[tid];
    sConst[CB63 + tid] = p.b63[tid];
    sConst[CB71 + tid] = p.b71[tid];
    sConst[CB72 + tid] = p.b72[tid];
    sConst[CB73 + tid] = p.b73[tid];
    sConst[CWPA + tid] = p.wpa[tid];
    sConst[CBPA + tid] = p.bpa[tid];
    sConst[CBPE + tid] = p.bpe[tid];
  }
  if (tid < 128) {
    sConst[CWPO + tid] = p.wpost[tid];
    sConst[CWPE + tid] = p.wpe[tid];
  }
  __syncthreads();

  u16* M   = sAct + wave * PW_U16;  // eP scratch in-iter; new-e carrier it0->it1
  u16* T1  = M + 1024;
  u16* T2  = M + 2048;
  u16* aPb = M + 3072;

  const float bpR = p.bpost[0], bpI = p.bpost[1];
  const int wslot = blockIdx.x * NWAVE + wave;

  for (int pi = 0; pi < PPW; ++pi) {
    const int g0 = (wslot * PPW + pi) * 2;   // 2 graphs: g0, g0+1
    if (g0 + 2 > p.gtot) break;

    // ---------------- pre-layer: a-rows and e-rows straight into registers ----------------
    const float apv = p.ap[(g0 + (n >> 3)) * 4 + ((n >> 1) & 3)];
    const frag2 A = make_a(apv, q, sConst);          // persists across both iterations
    short8_t e0, e1;
    {
      const float f0 = p.ef[(g0 + (n >> 3)) * 16 + (n & 7) * 2];
      const float f1 = p.ef[(g0 + (n >> 3)) * 16 + (n & 7) * 2 + 1];
#pragma unroll
      for (int h = 0; h < 2; ++h) {
        const int fb = 32 * h + 8 * q;
        const float4 w00 = *(const float4*)(sConst + CWPE + fb);
        const float4 w01 = *(const float4*)(sConst + CWPE + fb + 4);
        const float4 w10 = *(const float4*)(sConst + CWPE + 64 + fb);
        const float4 w11 = *(const float4*)(sConst + CWPE + 64 + fb + 4);
        const float4 be0 = *(const float4*)(sConst + CBPE + fb);
        const float4 be1 = *(const float4*)(sConst + CBPE + fb + 4);
        uint4 pe;
        pe.x = pk2(fmaxf(fmaf(f0, w00.x, fmaf(f1, w10.x, be0.x)), 0.f),
                   fmaxf(fmaf(f0, w00.y, fmaf(f1, w10.y, be0.y)), 0.f));
        pe.y = pk2(fmaxf(fmaf(f0, w00.z, fmaf(f1, w10.z, be0.z)), 0.f),
                   fmaxf(fmaf(f0, w00.w, fmaf(f1, w10.w, be0.w)), 0.f));
        pe.z = pk2(fmaxf(fmaf(f0, w01.x, fmaf(f1, w11.x, be1.x)), 0.f),
                   fmaxf(fmaf(f0, w01.y, fmaf(f1, w11.y, be1.y)), 0.f));
        pe.w = pk2(fmaxf(fmaf(f0, w01.z, fmaf(f1, w11.z, be1.z)), 0.f),
                   fmaxf(fmaf(f0, w01.w, fmaf(f1, w11.w, be1.w)), 0.f));
        if (h == 0) e0 = __builtin_bit_cast(short8_t, pe);
        else        e1 = __builtin_bit_cast(short8_t, pe);
      }
    }

    // ---- aP = a @ w61[:64]: iteration-invariant, A from regs ----
    {
      floatx4 accA[4];
#pragma unroll
      for (int t = 0; t < 4; ++t) { accA[t][0] = 0.f; accA[t][1] = 0.f; accA[t][2] = 0.f; accA[t][3] = 0.f; }
      layerK64R<4>(accA, A.f0, A.f1, sW + OFF_W61, l);
      scatter_aP(aPb, accA, q, n);
    }

    // ---------------- 2 shared-weight update iterations ----------------
#pragma unroll 1
    for (int it = 0; it < 2; ++it) {
      if (it == 1) { e0 = ldA(M, l); e1 = ldA(M + 512, l); }  // new e from it0

      // ---- eP layer first (independent of mlp5): hides under mlp5's chain ----
      {
        floatx4 accE[4];
#pragma unroll
        for (int t = 0; t < 4; ++t) { accE[t][0] = 0.f; accE[t][1] = 0.f; accE[t][2] = 0.f; accE[t][3] = 0.f; }
        layerK64R<4>(accE, e0, e1, sW + OFF_W61 + 2 * 512, l);
        scatter_bf16(M, accE, q, n);   // M = eP (dead before new-e write)
      }

      // ---- mlp5 -> m1 (T1 then T2) ----
      u32 m1p[8];
      {
        floatx4 acc[4]; init_accL(acc, sConst + CB51, n);
        layerK128R(acc, A.f0, A.f1, e0, e1, sW + OFF_W51, l);
        scatter_relu_bf16(T1, acc, q, n);
        floatx4 acc2[4]; init_accL(acc2, sConst + CB52, n);
        layerK64R<2>(acc2, ldA(T1, l), ldA(T1 + 512, l), sW + OFF_W52, l);
        scatter_relu_bf16(T2, acc2, q, n);
        floatx4 acc3[4]; init_accL(acc3, sConst + CB53, n);
        layerK64R<2>(acc3, ldA(T2, l), ldA(T2 + 512, l), sW + OFF_W53, l);
#pragma unroll
        for (int t = 0; t < 4; ++t) {
          m1p[2 * t + 0] = pk2(acc3[t][0], acc3[t][1]);
          m1p[2 * t + 1] = pk2(acc3[t][2], acc3[t][3]);
        }
      }

      // ---- mlp6 -> m2: bp FULLY unrolled, alternating scratch (T1/T2) ----
      u32 m2p[8];
#pragma unroll
      for (int i = 0; i < 8; ++i) m2p[i] = 0u;
      {
        const int d = n >> 1;
#pragma unroll
        for (int bp = 0; bp < 4; ++bp) {
          u16* Tb = (bp & 1) ? T2 : T1;
          const int re = (n & 8) + bp * 2 + (n & 1);
          short8_t h0, h1;
#pragma unroll
          for (int h = 0; h < 2; ++h) {
            const uint4 av = *(const uint4*)(aPb + h * 256 + (d + 8 * q) * 8);
            const uint4 ev = *(const uint4*)(M + h * 512 + (re + 16 * q) * 8);
            const float4 b0 = *(const float4*)(sConst + CB61 + 32 * h + 8 * q);
            const float4 b1 = *(const float4*)(sConst + CB61 + 32 * h + 8 * q + 4);
            uint4 ph;
            ph.x = pk2(fmaxf(blo(av.x) + blo(ev.x) + b0.x, 0.f),
                       fmaxf(bhi(av.x) + bhi(ev.x) + b0.y, 0.f));
            ph.y = pk2(fmaxf(blo(av.y) + blo(ev.y) + b0.z, 0.f),
                       fmaxf(bhi(av.y) + bhi(ev.y) + b0.w, 0.f));
            ph.z = pk2(fmaxf(blo(av.z) + blo(ev.z) + b1.x, 0.f),
                       fmaxf(bhi(av.z) + bhi(ev.z) + b1.y, 0.f));
            ph.w = pk2(fmaxf(blo(av.w) + blo(ev.w) + b1.z, 0.f),
                       fmaxf(bhi(av.w) + bhi(ev.w) + b1.w, 0.f));
            if (h == 0) h0 = __builtin_bit_cast(short8_t, ph);
            else        h1 = __builtin_bit_cast(short8_t, ph);
          }
          floatx4 acc2[4]; init_accL(acc2, sConst + CB62, n);
          layerK64R<2>(acc2, h0, h1, sW + OFF_W62, l);
          scatter_relu_bf16(Tb, acc2, q, n);
          floatx4 acc3[4]; init_accL(acc3, sConst + CB63, n);
          layerK64R<2>(acc3, ldA(Tb, l), ldA(Tb + 512, l), sW + OFF_W63, l);
#pragma unroll
          for (int t = 0; t < 4; ++t) {
#pragma unroll
            for (int h = 0; h < 2; ++h) {
              const u32 cand = pk2(acc3[t][2 * h], acc3[t][2 * h + 1]);
              const u32 mx = pkmax(m2p[2 * t + h], cand);
              m2p[2 * t + h] = (((2 * q + h) & 3) != bp) ? mx : m2p[2 * t + h];
            }
          }
        }
      }

      // ---- agg + mlp7 (T1 -> T2 -> T1) ----
      {
        u32 agp[8];
#pragma unroll
        for (int i = 0; i < 8; ++i) agp[i] = pkmax(ror16(m1p[i]), m2p[i]);
        scatter_pk(T1, agp, q, n);
        floatx4 acc[4]; init_accL(acc, sConst + CB71, n);
        layerK128R(acc, ldA(T1, l), ldA(T1 + 512, l), e0, e1, sW + OFF_W71, l);
        scatter_relu_bf16(T2, acc, q, n);
        floatx4 acc2[4]; init_accL(acc2, sConst + CB72, n);
        layerK64R<2>(acc2, ldA(T2, l), ldA(T2 + 512, l), sW + OFF_W72, l);
        scatter_relu_bf16(T1, acc2, q, n);
        floatx4 acc3[4]; init_accL(acc3, sConst + CB73, n);
        layerK64R<2>(acc3, ldA(T1, l), ldA(T1 + 512, l), sW + OFF_W73, l);

        if (it == 0) {
          scatter_relu_bf16(M, acc3, q, n);   // new e -> M (eP dead now)
        } else {
          // ---- post linear + per-(g,b) L2 row normalization ----
          float prr[4] = {0.f, 0.f, 0.f, 0.f}, pii[4] = {0.f, 0.f, 0.f, 0.f};
#pragma unroll
          for (int t = 0; t < 4; ++t) {
            const float wr = sConst[CWPO + (16 * t + n) * 2];
            const float wi = sConst[CWPO + (16 * t + n) * 2 + 1];
#pragma unroll
            for (int r = 0; r < 4; ++r) {
              const float e = fmaxf(acc3[t][r], 0.f);
              prr[r] = fmaf(e, wr, prr[r]);
              pii[r] = fmaf(e, wi, pii[r]);
            }
          }
#pragma unroll
          for (int r = 0; r < 4; ++r) {
#pragma unroll
            for (int off = 1; off < 16; off <<= 1) {
              prr[r] += __shfl_xor(prr[r], off, 16);
              pii[r] += __shfl_xor(pii[r], off, 16);
            }
            prr[r] += bpR;
            pii[r] += bpI;
          }
          const int r = n >> 1, c = n & 1, rp = r ^ 1;
          const float pr_r  = sel4(r,  prr[0], prr[1], prr[2], prr[3]);
          const float pi_r  = sel4(r,  pii[0], pii[1], pii[2], pii[3]);
          const float pr_rp = sel4(rp, prr[0], prr[1], prr[2], prr[3]);
          const float pi_rp = sel4(rp, pii[0], pii[1], pii[2], pii[3]);
          const float num = c ? pi_r : pr_r;
          const float n2  = pr_r * pr_r + pi_r * pi_r + pr_rp * pr_rp + pi_rp * pi_rp;
          if (n < 8) p.out[g0 * 16 + (4 * q + r) * 2 + c] = num / sqrtf(n2);
        }
      }
    }
  }
}

extern "C" void kernel_launch(void* const* d_in, const int* in_sizes, int n_in,
                              void* d_out, int out_size, void* d_ws, size_t ws_size,
                              hipStream_t stream) {
  Params p;
  p.ap    = (const float*)d_in[0];
  p.ef    = (const float*)d_in[1];
  p.wpa   = (const float*)d_in[2];  p.bpa   = (const float*)d_in[3];
  p.wpe   = (const float*)d_in[4];  p.bpe   = (const float*)d_in[5];
  p.w51   = (const float*)d_in[6];  p.b51   = (const float*)d_in[7];
  p.w52   = (const float*)d_in[8];  p.b52   = (const float*)d_in[9];
  p.w53   = (const float*)d_in[10]; p.b53   = (const float*)d_in[11];
  p.w61   = (const float*)d_in[12]; p.b61   = (const float*)d_in[13];
  p.w62   = (const float*)d_in[14]; p.b62   = (const float*)d_in[15];
  p.w63   = (const float*)d_in[16]; p.b63   = (const float*)d_in[17];
  p.w71   = (const float*)d_in[18]; p.b71   = (const float*)d_in[19];
  p.w72   = (const float*)d_in[20]; p.b72   = (const float*)d_in[21];
  p.w73   = (const float*)d_in[22]; p.b73   = (const float*)d_in[23];
  p.wpost = (const float*)d_in[24]; p.bpost = (const float*)d_in[25];
  p.out   = (float*)d_out;
  p.gtot  = in_sizes[0] / 4;  // G from ap_feat [G,B,1]

  hipLaunchKernelGGL(hetgnn_mfma, dim3(NBLK), dim3(512), 0, stream, p);
}

// Round 12
// 178.035 us; speedup vs baseline: 1.1318x; 1.0274x over previous
//
#include <hip/hip_runtime.h>

// HetGNN fused kernel, round 12: R9 structure (best known, 95us) + cheap pack.
// R11's ILP package regressed (112us, both busy metrics down -> code bloat);
// reverted. This round tests the R8 debt: VALUBusy arithmetic says ~61K VALU
// slots/wave vs ~6K intentional -> suspect the software-RNE f2bf fallback
// (~10-12 VALU per packed pair x ~1000 pairs/wave). Change: pk2 = (+0x8000,
// +0x8000, v_perm_b32) = 3 VALU unconditionally (round-half-up; differs from
// RNE only on exact ties by 1 bf16 ULP -- absmax may move off 0.00390625).

typedef unsigned short u16;
typedef unsigned int   u32;
typedef __attribute__((ext_vector_type(8))) short short8_t;
typedef __attribute__((ext_vector_type(2))) short short2v;
typedef __attribute__((ext_vector_type(4))) float floatx4;

// u16 offsets of each matrix's fragment block inside sW (fi*512 ordering).
#define OFF_W51 0
#define OFF_W61 8192
#define OFF_W71 16384
#define OFF_W52 24576
#define OFF_W53 28672
#define OFF_W62 32768
#define OFF_W63 36864
#define OFF_W72 40960
#define OFF_W73 45056
#define WS_U16  49152

// f32 offsets inside the sConst LDS table.
#define CB51 0
#define CB52 64
#define CB53 128
#define CB61 192
#define CB62 256
#define CB63 320
#define CB71 384
#define CB72 448
#define CB73 512
#define CWPO 576
#define CBPO 704
#define CWPA 768
#define CBPA 832
#define CWPE 896
#define CBPE 1024
#define CSZ  1088

#define PW_U16 3584   // per-wave LDS: Eb 1024 | T1 1024 | eP 1024 | aPb 512

struct Params {
  const float *ap, *ef;
  const float *wpa, *bpa, *wpe, *bpe;
  const float *w51, *b51, *w52, *b52, *w53, *b53;
  const float *w61, *b61, *w62, *b62, *w63, *b63;
  const float *w71, *b71, *w72, *b72, *w73, *b73;
  const float *wpost, *bpost;
  float *out;
  int gtot;
};

// Pack two f32 to bf16 pair: round-half-up via +0x8000, then one byte-perm.
// 3 VALU total (vs ~10-12 for the software-RNE fallback).
__device__ __forceinline__ u32 pk2(float a, float b) {
  const u32 ua = __float_as_uint(a) + 0x8000u;
  const u32 ub = __float_as_uint(b) + 0x8000u;
  return __builtin_amdgcn_perm(ub, ua, 0x07060302u);  // {ub[31:16], ua[31:16]}
}
__device__ __forceinline__ float blo(u32 v) { return __uint_as_float(v << 16); }
__device__ __forceinline__ float bhi(u32 v) { return __uint_as_float(v & 0xffff0000u); }
// packed int16 max: valid as bf16 max when one side >= 0 (our running vals).
__device__ __forceinline__ u32 pkmax(u32 a, u32 b) {
  const short2v r = __builtin_elementwise_max(__builtin_bit_cast(short2v, a),
                                              __builtin_bit_cast(short2v, b));
  return __builtin_bit_cast(u32, r);
}
__device__ __forceinline__ u32 ror16(u32 x) { return (x >> 16) | (x << 16); }
__device__ __forceinline__ float sel4(int i, float x0, float x1, float x2, float x3) {
  const float lo = (i & 1) ? x1 : x0;
  const float hi = (i & 1) ? x3 : x2;
  return (i & 2) ? hi : lo;
}

__device__ __forceinline__ floatx4 mfma16(short8_t a, short8_t b, floatx4 c) {
  return __builtin_amdgcn_mfma_f32_16x16x32_bf16(a, b, c, 0, 0, 0);
}
__device__ __forceinline__ short8_t ldA(const u16* buf, int l) {
  return *(const short8_t*)(buf + l * 8);
}

template<int TSTRIDE>
__device__ __forceinline__ void layerK64R(floatx4* acc, short8_t a0, short8_t a1,
                                          const u16* B, int l) {
#pragma unroll
  for (int t = 0; t < 4; ++t) {
    const short8_t b0 = *(const short8_t*)(B + (t * TSTRIDE + 0) * 512 + l * 8);
    const short8_t b1 = *(const short8_t*)(B + (t * TSTRIDE + 1) * 512 + l * 8);
    acc[t] = mfma16(a0, b0, acc[t]);
    acc[t] = mfma16(a1, b1, acc[t]);
  }
}

__device__ __forceinline__ void layerK128R(floatx4* acc, short8_t a0, short8_t a1,
                                           short8_t a2, short8_t a3,
                                           const u16* B, int l) {
  short8_t a[4] = {a0, a1, a2, a3};
#pragma unroll
  for (int t = 0; t < 4; ++t)
#pragma unroll
    for (int h = 0; h < 4; ++h)
      acc[t] = mfma16(a[h], *(const short8_t*)(B + (t * 4 + h) * 512 + l * 8), acc[t]);
}

// C-layout regs -> A-frag-swizzled bf16 LDS (with relu). Element (m=4q+r, f=16t+n).
__device__ __forceinline__ void scatter_relu_bf16(u16* dst, const floatx4* acc, int q, int n) {
#pragma unroll
  for (int t = 0; t < 4; ++t) {
    const int kk = (t & 1) * 2 + (n >> 3);
    u16* base = dst + (t >> 1) * 512 + (n & 7);
    const u32 v01 = pk2(fmaxf(acc[t][0], 0.f), fmaxf(acc[t][1], 0.f));
    const u32 v23 = pk2(fmaxf(acc[t][2], 0.f), fmaxf(acc[t][3], 0.f));
    base[(4 * q + 0 + 16 * kk) * 8] = (u16)v01;
    base[(4 * q + 1 + 16 * kk) * 8] = (u16)(v01 >> 16);
    base[(4 * q + 2 + 16 * kk) * 8] = (u16)v23;
    base[(4 * q + 3 + 16 * kk) * 8] = (u16)(v23 >> 16);
  }
}

// Same, no relu (eP can be negative).
__device__ __forceinline__ void scatter_bf16(u16* dst, const floatx4* acc, int q, int n) {
#pragma unroll
  for (int t = 0; t < 4; ++t) {
    const int kk = (t & 1) * 2 + (n >> 3);
    u16* base = dst + (t >> 1) * 512 + (n & 7);
    const u32 v01 = pk2(acc[t][0], acc[t][1]);
    const u32 v23 = pk2(acc[t][2], acc[t][3]);
    base[(4 * q + 0 + 16 * kk) * 8] = (u16)v01;
    base[(4 * q + 1 + 16 * kk) * 8] = (u16)(v01 >> 16);
    base[(4 * q + 2 + 16 * kk) * 8] = (u16)v23;
    base[(4 * q + 3 + 16 * kk) * 8] = (u16)(v23 >> 16);
  }
}

// Packed src: src[2t+half] holds rows (4q+2half, 4q+2half+1).
__device__ __forceinline__ void scatter_pk(u16* dst, const u32* src, int q, int n) {
#pragma unroll
  for (int t = 0; t < 4; ++t) {
    const int kk = (t & 1) * 2 + (n >> 3);
    u16* base = dst + (t >> 1) * 512 + (n & 7);
#pragma unroll
    for (int half = 0; half < 2; ++half) {
      const u32 v = src[2 * t + half];
      base[(4 * q + 2 * half + 0 + 16 * kk) * 8] = (u16)v;
      base[(4 * q + 2 * half + 1 + 16 * kk) * 8] = (u16)(v >> 16);
    }
  }
}

// aP dedup scatter (8 rows): region t>>1, chunk (2q+half + 8kk), word n&7.
__device__ __forceinline__ void scatter_aP(u16* dst, const floatx4* acc, int q, int n) {
#pragma unroll
  for (int t = 0; t < 4; ++t) {
    const int kk = (t & 1) * 2 + (n >> 3);
    u16* base = dst + (t >> 1) * 256 + (n & 7);
    const u32 v = pk2(acc[t][0], acc[t][2]);   // rows 4q,4q+2 -> d=2q,2q+1
    base[(2 * q + 0 + 8 * kk) * 8] = (u16)v;
    base[(2 * q + 1 + 8 * kk) * 8] = (u16)(v >> 16);
  }
}

__device__ __forceinline__ void init_accL(floatx4* acc, const float* cb, int n) {
#pragma unroll
  for (int t = 0; t < 4; ++t) {
    const float b = cb[16 * t + n];
    floatx4 v; v[0] = b; v[1] = b; v[2] = b; v[3] = b;
    acc[t] = v;
  }
}

struct frag2 { short8_t f0, f1; };

__device__ __forceinline__ frag2 make_a(float apv, int q, const float* sc) {
  frag2 r;
#pragma unroll
  for (int h = 0; h < 2; ++h) {
    const int fb = 32 * h + 8 * q;
    const float4 wa0 = *(const float4*)(sc + CWPA + fb);
    const float4 wa1 = *(const float4*)(sc + CWPA + fb + 4);
    const float4 ba0 = *(const float4*)(sc + CBPA + fb);
    const float4 ba1 = *(const float4*)(sc + CBPA + fb + 4);
    uint4 pa;
    pa.x = pk2(fmaxf(fmaf(apv, wa0.x, ba0.x), 0.f), fmaxf(fmaf(apv, wa0.y, ba0.y), 0.f));
    pa.y = pk2(fmaxf(fmaf(apv, wa0.z, ba0.z), 0.f), fmaxf(fmaf(apv, wa0.w, ba0.w), 0.f));
    pa.z = pk2(fmaxf(fmaf(apv, wa1.x, ba1.x), 0.f), fmaxf(fmaf(apv, wa1.y, ba1.y), 0.f));
    pa.w = pk2(fmaxf(fmaf(apv, wa1.z, ba1.z), 0.f), fmaxf(fmaf(apv, wa1.w, ba1.w), 0.f));
    if (h == 0) r.f0 = __builtin_bit_cast(short8_t, pa);
    else        r.f1 = __builtin_bit_cast(short8_t, pa);
  }
  return r;
}

#define NBLK 256
#define NWAVE 8
#define PPW  4   // 256 blk * 8 waves * 4 pairs = 8192 pairs = 16384 graphs

__global__ __launch_bounds__(512)
__attribute__((amdgpu_waves_per_eu(2)))
void hetgnn_mfma(Params p) {
  __shared__ __align__(16) u16   sW[WS_U16];            // 96 KB weights
  __shared__ __align__(16) u16   sAct[NWAVE * PW_U16];  // 56 KB: 8 x (Eb|T1|eP|aPb)
  __shared__ __align__(16) float sConst[CSZ];           // 4.25 KB

  const int tid  = threadIdx.x;
  const int wave = tid >> 6;
  const int l    = tid & 63;
  const int q    = l >> 4;
  const int n    = l & 15;

  // ---- stage + swizzle weights (f32 global -> bf16 B-frag LDS), 12 frags/wave ----
  {
    const float* mats[9] = {p.w51, p.w61, p.w71, p.w52, p.w53, p.w62, p.w63, p.w72, p.w73};
    for (int i = 0; i < 12; ++i) {
      const int fi = wave * 12 + i;   // wave-uniform, 0..95
      const float* W;
      int t, h;
      if (fi < 48) { W = mats[fi >> 4]; const int loc = fi & 15; t = loc >> 2; h = loc & 3; }
      else { const int j = fi - 48; W = mats[3 + (j >> 3)]; const int loc = j & 7; t = loc >> 1; h = loc & 1; }
      const int nn = 16 * t + (l & 15);
      const int k0 = 32 * h + (l >> 4) * 8;
      float w[8];
#pragma unroll
      for (int j = 0; j < 8; ++j) w[j] = W[(k0 + j) * 64 + nn];
      uint4 o;
      o.x = pk2(w[0], w[1]); o.y = pk2(w[2], w[3]);
      o.z = pk2(w[4], w[5]); o.w = pk2(w[6], w[7]);
      *(uint4*)(sW + fi * 512 + l * 8) = o;
    }
  }
  if (tid < 64) {
    sConst[CB51 + tid] = p.b51[tid];
    sConst[CB52 + tid] = p.b52[tid];
    sConst[CB53 + tid] = p.b53[tid];
    sConst[CB61 + tid] = p.b61[tid];
    sConst[CB62 + tid] = p.b62[tid];
    sConst[CB63 + tid] = p.b63[tid];
    sConst[CB71 + tid] = p.b71[tid];
    sConst[CB72 + tid] = p.b72[tid];
    sConst[CB73 + tid] = p.b73[tid];
    sConst[CWPA + tid] = p.wpa[tid];
    sConst[CBPA + tid] = p.bpa[tid];
    sConst[CBPE + tid] = p.bpe[tid];
  }
  if (tid < 128) {
    sConst[CWPO + tid] = p.wpost[tid];
    sConst[CWPE + tid] = p.wpe[tid];
  }
  if (tid < 2) sConst[CBPO + tid] = p.bpost[tid];
  __syncthreads();

  u16* Eb  = sAct + wave * PW_U16;   // new-e (written by it0's final scatter only)
  u16* T1  = Eb + 1024;
  u16* eP  = Eb + 2048;
  u16* aPb = Eb + 3072;

  const int wslot = blockIdx.x * NWAVE + wave;

  for (int pi = 0; pi < PPW; ++pi) {
    const int g0 = (wslot * PPW + pi) * 2;   // 2 graphs: g0, g0+1
    if (g0 + 2 > p.gtot) break;

    // ---------------- pre-layer: a-rows and e-rows straight into registers ----------------
    const float apv = p.ap[(g0 + (n >> 3)) * 4 + ((n >> 1) & 3)];
    const frag2 A = make_a(apv, q, sConst);          // persists across both iterations
    short8_t e0, e1;
    {
      const float f0 = p.ef[(g0 + (n >> 3)) * 16 + (n & 7) * 2];
      const float f1 = p.ef[(g0 + (n >> 3)) * 16 + (n & 7) * 2 + 1];
#pragma unroll
      for (int h = 0; h < 2; ++h) {
        const int fb = 32 * h + 8 * q;
        const float4 w00 = *(const float4*)(sConst + CWPE + fb);
        const float4 w01 = *(const float4*)(sConst + CWPE + fb + 4);
        const float4 w10 = *(const float4*)(sConst + CWPE + 64 + fb);
        const float4 w11 = *(const float4*)(sConst + CWPE + 64 + fb + 4);
        const float4 be0 = *(const float4*)(sConst + CBPE + fb);
        const float4 be1 = *(const float4*)(sConst + CBPE + fb + 4);
        uint4 pe;
        pe.x = pk2(fmaxf(fmaf(f0, w00.x, fmaf(f1, w10.x, be0.x)), 0.f),
                   fmaxf(fmaf(f0, w00.y, fmaf(f1, w10.y, be0.y)), 0.f));
        pe.y = pk2(fmaxf(fmaf(f0, w00.z, fmaf(f1, w10.z, be0.z)), 0.f),
                   fmaxf(fmaf(f0, w00.w, fmaf(f1, w10.w, be0.w)), 0.f));
        pe.z = pk2(fmaxf(fmaf(f0, w01.x, fmaf(f1, w11.x, be1.x)), 0.f),
                   fmaxf(fmaf(f0, w01.y, fmaf(f1, w11.y, be1.y)), 0.f));
        pe.w = pk2(fmaxf(fmaf(f0, w01.z, fmaf(f1, w11.z, be1.z)), 0.f),
                   fmaxf(fmaf(f0, w01.w, fmaf(f1, w11.w, be1.w)), 0.f));
        if (h == 0) e0 = __builtin_bit_cast(short8_t, pe);
        else        e1 = __builtin_bit_cast(short8_t, pe);
      }
    }

    // ---- aP = a @ w61[:64]: iteration-invariant, A from regs ----
    {
      floatx4 accA[4];
#pragma unroll
      for (int t = 0; t < 4; ++t) { accA[t][0] = 0.f; accA[t][1] = 0.f; accA[t][2] = 0.f; accA[t][3] = 0.f; }
      layerK64R<4>(accA, A.f0, A.f1, sW + OFF_W61, l);
      scatter_aP(aPb, accA, q, n);
    }

    // ---------------- 2 shared-weight update iterations ----------------
#pragma unroll 1
    for (int it = 0; it < 2; ++it) {
      if (it == 1) { e0 = ldA(Eb, l); e1 = ldA(Eb + 512, l); }  // new e from it0

      // ---- mlp5 -> m1 (packed raw bf16; relu deferred to max) ----
      u32 m1p[8];
      {
        floatx4 acc[4]; init_accL(acc, sConst + CB51, n);
        layerK128R(acc, A.f0, A.f1, e0, e1, sW + OFF_W51, l);
        scatter_relu_bf16(T1, acc, q, n);
        floatx4 acc2[4]; init_accL(acc2, sConst + CB52, n);
        layerK64R<2>(acc2, ldA(T1, l), ldA(T1 + 512, l), sW + OFF_W52, l);
        scatter_relu_bf16(T1, acc2, q, n);
        floatx4 acc3[4]; init_accL(acc3, sConst + CB53, n);
        layerK64R<2>(acc3, ldA(T1, l), ldA(T1 + 512, l), sW + OFF_W53, l);
#pragma unroll
        for (int t = 0; t < 4; ++t) {
          m1p[2 * t + 0] = pk2(acc3[t][0], acc3[t][1]);
          m1p[2 * t + 1] = pk2(acc3[t][2], acc3[t][3]);
        }
      }

      // ---- mlp6 -> m2 (masked running max; h in regs) ----
      u32 m2p[8];
#pragma unroll
      for (int i = 0; i < 8; ++i) m2p[i] = 0u;
      {
        floatx4 accE[4];
#pragma unroll
        for (int t = 0; t < 4; ++t) { accE[t][0] = 0.f; accE[t][1] = 0.f; accE[t][2] = 0.f; accE[t][3] = 0.f; }
        layerK64R<4>(accE, e0, e1, sW + OFF_W61 + 2 * 512, l);
        scatter_bf16(eP, accE, q, n);

        const int d = n >> 1;
#pragma unroll 2
        for (int bp = 0; bp < 4; ++bp) {
          const int re = (n & 8) + bp * 2 + (n & 1);
          short8_t h0, h1;
#pragma unroll
          for (int h = 0; h < 2; ++h) {
            const uint4 av = *(const uint4*)(aPb + h * 256 + (d + 8 * q) * 8);
            const uint4 ev = *(const uint4*)(eP + h * 512 + (re + 16 * q) * 8);
            const float4 b0 = *(const float4*)(sConst + CB61 + 32 * h + 8 * q);
            const float4 b1 = *(const float4*)(sConst + CB61 + 32 * h + 8 * q + 4);
            uint4 ph;
            ph.x = pk2(fmaxf(blo(av.x) + blo(ev.x) + b0.x, 0.f),
                       fmaxf(bhi(av.x) + bhi(ev.x) + b0.y, 0.f));
            ph.y = pk2(fmaxf(blo(av.y) + blo(ev.y) + b0.z, 0.f),
                       fmaxf(bhi(av.y) + bhi(ev.y) + b0.w, 0.f));
            ph.z = pk2(fmaxf(blo(av.z) + blo(ev.z) + b1.x, 0.f),
                       fmaxf(bhi(av.z) + bhi(ev.z) + b1.y, 0.f));
            ph.w = pk2(fmaxf(blo(av.w) + blo(ev.w) + b1.z, 0.f),
                       fmaxf(bhi(av.w) + bhi(ev.w) + b1.w, 0.f));
            if (h == 0) h0 = __builtin_bit_cast(short8_t, ph);
            else        h1 = __builtin_bit_cast(short8_t, ph);
          }
          floatx4 acc2[4]; init_accL(acc2, sConst + CB62, n);
          layerK64R<2>(acc2, h0, h1, sW + OFF_W62, l);
          scatter_relu_bf16(T1, acc2, q, n);
          floatx4 acc3[4]; init_accL(acc3, sConst + CB63, n);
          layerK64R<2>(acc3, ldA(T1, l), ldA(T1 + 512, l), sW + OFF_W63, l);
#pragma unroll
          for (int t = 0; t < 4; ++t) {
#pragma unroll
            for (int h = 0; h < 2; ++h) {
              const u32 cand = pk2(acc3[t][2 * h], acc3[t][2 * h + 1]);
              const u32 mx = pkmax(m2p[2 * t + h], cand);
              m2p[2 * t + h] = (((2 * q + h) & 3) != bp) ? mx : m2p[2 * t + h];
            }
          }
        }
      }

      // ---- agg (packed) + mlp7 ----
      {
        u32 agp[8];
#pragma unroll
        for (int i = 0; i < 8; ++i) agp[i] = pkmax(ror16(m1p[i]), m2p[i]);
        scatter_pk(T1, agp, q, n);
        floatx4 acc[4]; init_accL(acc, sConst + CB71, n);
        layerK128R(acc, ldA(T1, l), ldA(T1 + 512, l), e0, e1, sW + OFF_W71, l);
        scatter_relu_bf16(T1, acc, q, n);
        floatx4 acc2[4]; init_accL(acc2, sConst + CB72, n);
        layerK64R<2>(acc2, ldA(T1, l), ldA(T1 + 512, l), sW + OFF_W72, l);
        scatter_relu_bf16(T1, acc2, q, n);
        floatx4 acc3[4]; init_accL(acc3, sConst + CB73, n);
        layerK64R<2>(acc3, ldA(T1, l), ldA(T1 + 512, l), sW + OFF_W73, l);

        if (it == 0) {
          scatter_relu_bf16(Eb, acc3, q, n);   // new e (cross-lane -> LDS)
        } else {
          // ---- post linear + per-(g,b) L2 row normalization ----
          float prr[4] = {0.f, 0.f, 0.f, 0.f}, pii[4] = {0.f, 0.f, 0.f, 0.f};
#pragma unroll
          for (int t = 0; t < 4; ++t) {
            const float wr = sConst[CWPO + (16 * t + n) * 2];
            const float wi = sConst[CWPO + (16 * t + n) * 2 + 1];
#pragma unroll
            for (int r = 0; r < 4; ++r) {
              const float e = fmaxf(acc3[t][r], 0.f);
              prr[r] = fmaf(e, wr, prr[r]);
              pii[r] = fmaf(e, wi, pii[r]);
            }
          }
          const float bpR = sConst[CBPO], bpI = sConst[CBPO + 1];
#pragma unroll
          for (int r = 0; r < 4; ++r) {
#pragma unroll
            for (int off = 1; off < 16; off <<= 1) {
              prr[r] += __shfl_xor(prr[r], off, 16);
              pii[r] += __shfl_xor(pii[r], off, 16);
            }
            prr[r] += bpR;
            pii[r] += bpI;
          }
          const int r = n >> 1, c = n & 1, rp = r ^ 1;
          const float pr_r  = sel4(r,  prr[0], prr[1], prr[2], prr[3]);
          const float pi_r  = sel4(r,  pii[0], pii[1], pii[2], pii[3]);
          const float pr_rp = sel4(rp, prr[0], prr[1], prr[2], prr[3]);
          const float pi_rp = sel4(rp, pii[0], pii[1], pii[2], pii[3]);
          const float num = c ? pi_r : pr_r;
          const float n2  = pr_r * pr_r + pi_r * pi_r + pr_rp * pr_rp + pi_rp * pi_rp;
          if (n < 8) p.out[g0 * 16 + (4 * q + r) * 2 + c] = num / sqrtf(n2);
        }
      }
    }
  }
}

extern "C" void kernel_launch(void* const* d_in, const int* in_sizes, int n_in,
                              void* d_out, int out_size, void* d_ws, size_t ws_size,
                              hipStream_t stream) {
  Params p;
  p.ap    = (const float*)d_in[0];
  p.ef    = (const float*)d_in[1];
  p.wpa   = (const float*)d_in[2];  p.bpa   = (const float*)d_in[3];
  p.wpe   = (const float*)d_in[4];  p.bpe   = (const float*)d_in[5];
  p.w51   = (const float*)d_in[6];  p.b51   = (const float*)d_in[7];
  p.w52   = (const float*)d_in[8];  p.b52   = (const float*)d_in[9];
  p.w53   = (const float*)d_in[10]; p.b53   = (const float*)d_in[11];
  p.w61   = (const float*)d_in[12]; p.b61   = (const float*)d_in[13];
  p.w62   = (const float*)d_in[14]; p.b62   = (const float*)d_in[15];
  p.w63   = (const float*)d_in[16]; p.b63   = (const float*)d_in[17];
  p.w71   = (const float*)d_in[18]; p.b71   = (const float*)d_in[19];
  p.w72   = (const float*)d_in[20]; p.b72   = (const float*)d_in[21];
  p.w73   = (const float*)d_in[22]; p.b73   = (const float*)d_in[23];
  p.wpost = (const float*)d_in[24]; p.bpost = (const float*)d_in[25];
  p.out   = (float*)d_out;
  p.gtot  = in_sizes[0] / 4;  // G from ap_feat [G,B,1]

  hipLaunchKernelGGL(hetgnn_mfma, dim3(NBLK), dim3(512), 0, stream, p);
}

// Round 13
// 175.057 us; speedup vs baseline: 1.1510x; 1.0170x over previous
//
#include <hip/hip_runtime.h>

// HetGNN fused kernel, round 13: attack the LDS pipe (the newly-identified
// saturated resource). R12 arithmetic: ~170 ds_read_b128/pair-it x 12cyc ->
// ~180K LDS cycles/CU vs 204K total budget => LDS-throughput bound (explains
// R8: conflict elimination changed nothing -- conflict-free b128s still pay
// full BW). Changes vs R12 (85us):
//  1. W62/W63 B-frags cached in VGPRs (16 frags = 64 regs, loaded once per
//     wave): removes 64 of 136 B-frag LDS reads per pair-iteration (these
//     weights are read 8x per pair -- highest reuse).
//  2. b61 pre-folded into aPb at scatter (one extra bf16 rounding): removes
//     32 b61 ds_reads/pair + 8 VALU adds per h-frag.

typedef unsigned short u16;
typedef unsigned int   u32;
typedef __attribute__((ext_vector_type(8))) short short8_t;
typedef __attribute__((ext_vector_type(2))) short short2v;
typedef __attribute__((ext_vector_type(4))) float floatx4;

// u16 offsets of each matrix's fragment block inside sW (fi*512 ordering).
#define OFF_W51 0
#define OFF_W61 8192
#define OFF_W71 16384
#define OFF_W52 24576
#define OFF_W53 28672
#define OFF_W62 32768
#define OFF_W63 36864
#define OFF_W72 40960
#define OFF_W73 45056
#define WS_U16  49152

// f32 offsets inside the sConst LDS table.
#define CB51 0
#define CB52 64
#define CB53 128
#define CB61 192
#define CB62 256
#define CB63 320
#define CB71 384
#define CB72 448
#define CB73 512
#define CWPO 576
#define CBPO 704
#define CWPA 768
#define CBPA 832
#define CWPE 896
#define CBPE 1024
#define CSZ  1088

#define PW_U16 3584   // per-wave LDS: Eb 1024 | T1 1024 | eP 1024 | aPb 512

struct Params {
  const float *ap, *ef;
  const float *wpa, *bpa, *wpe, *bpe;
  const float *w51, *b51, *w52, *b52, *w53, *b53;
  const float *w61, *b61, *w62, *b62, *w63, *b63;
  const float *w71, *b71, *w72, *b72, *w73, *b73;
  const float *wpost, *bpost;
  float *out;
  int gtot;
};

// Pack two f32 to bf16 pair: round-half-up via +0x8000, then one byte-perm.
__device__ __forceinline__ u32 pk2(float a, float b) {
  const u32 ua = __float_as_uint(a) + 0x8000u;
  const u32 ub = __float_as_uint(b) + 0x8000u;
  return __builtin_amdgcn_perm(ub, ua, 0x07060302u);  // {ub[31:16], ua[31:16]}
}
__device__ __forceinline__ float blo(u32 v) { return __uint_as_float(v << 16); }
__device__ __forceinline__ float bhi(u32 v) { return __uint_as_float(v & 0xffff0000u); }
// packed int16 max: valid as bf16 max when one side >= 0 (our running vals).
__device__ __forceinline__ u32 pkmax(u32 a, u32 b) {
  const short2v r = __builtin_elementwise_max(__builtin_bit_cast(short2v, a),
                                              __builtin_bit_cast(short2v, b));
  return __builtin_bit_cast(u32, r);
}
__device__ __forceinline__ u32 ror16(u32 x) { return (x >> 16) | (x << 16); }
__device__ __forceinline__ float sel4(int i, float x0, float x1, float x2, float x3) {
  const float lo = (i & 1) ? x1 : x0;
  const float hi = (i & 1) ? x3 : x2;
  return (i & 2) ? hi : lo;
}

__device__ __forceinline__ floatx4 mfma16(short8_t a, short8_t b, floatx4 c) {
  return __builtin_amdgcn_mfma_f32_16x16x32_bf16(a, b, c, 0, 0, 0);
}
__device__ __forceinline__ short8_t ldA(const u16* buf, int l) {
  return *(const short8_t*)(buf + l * 8);
}

template<int TSTRIDE>
__device__ __forceinline__ void layerK64R(floatx4* acc, short8_t a0, short8_t a1,
                                          const u16* B, int l) {
#pragma unroll
  for (int t = 0; t < 4; ++t) {
    const short8_t b0 = *(const short8_t*)(B + (t * TSTRIDE + 0) * 512 + l * 8);
    const short8_t b1 = *(const short8_t*)(B + (t * TSTRIDE + 1) * 512 + l * 8);
    acc[t] = mfma16(a0, b0, acc[t]);
    acc[t] = mfma16(a1, b1, acc[t]);
  }
}

// K=64 layer with B-frags from REGISTERS (no LDS traffic).
__device__ __forceinline__ void layerK64B(floatx4* acc, short8_t a0, short8_t a1,
                                          const short8_t* Bw) {
#pragma unroll
  for (int t = 0; t < 4; ++t) {
    acc[t] = mfma16(a0, Bw[2 * t + 0], acc[t]);
    acc[t] = mfma16(a1, Bw[2 * t + 1], acc[t]);
  }
}

__device__ __forceinline__ void layerK128R(floatx4* acc, short8_t a0, short8_t a1,
                                           short8_t a2, short8_t a3,
                                           const u16* B, int l) {
  short8_t a[4] = {a0, a1, a2, a3};
#pragma unroll
  for (int t = 0; t < 4; ++t)
#pragma unroll
    for (int h = 0; h < 4; ++h)
      acc[t] = mfma16(a[h], *(const short8_t*)(B + (t * 4 + h) * 512 + l * 8), acc[t]);
}

// C-layout regs -> A-frag-swizzled bf16 LDS (with relu). Element (m=4q+r, f=16t+n).
__device__ __forceinline__ void scatter_relu_bf16(u16* dst, const floatx4* acc, int q, int n) {
#pragma unroll
  for (int t = 0; t < 4; ++t) {
    const int kk = (t & 1) * 2 + (n >> 3);
    u16* base = dst + (t >> 1) * 512 + (n & 7);
    const u32 v01 = pk2(fmaxf(acc[t][0], 0.f), fmaxf(acc[t][1], 0.f));
    const u32 v23 = pk2(fmaxf(acc[t][2], 0.f), fmaxf(acc[t][3], 0.f));
    base[(4 * q + 0 + 16 * kk) * 8] = (u16)v01;
    base[(4 * q + 1 + 16 * kk) * 8] = (u16)(v01 >> 16);
    base[(4 * q + 2 + 16 * kk) * 8] = (u16)v23;
    base[(4 * q + 3 + 16 * kk) * 8] = (u16)(v23 >> 16);
  }
}

// Same, no relu (eP can be negative).
__device__ __forceinline__ void scatter_bf16(u16* dst, const floatx4* acc, int q, int n) {
#pragma unroll
  for (int t = 0; t < 4; ++t) {
    const int kk = (t & 1) * 2 + (n >> 3);
    u16* base = dst + (t >> 1) * 512 + (n & 7);
    const u32 v01 = pk2(acc[t][0], acc[t][1]);
    const u32 v23 = pk2(acc[t][2], acc[t][3]);
    base[(4 * q + 0 + 16 * kk) * 8] = (u16)v01;
    base[(4 * q + 1 + 16 * kk) * 8] = (u16)(v01 >> 16);
    base[(4 * q + 2 + 16 * kk) * 8] = (u16)v23;
    base[(4 * q + 3 + 16 * kk) * 8] = (u16)(v23 >> 16);
  }
}

// Packed src: src[2t+half] holds rows (4q+2half, 4q+2half+1).
__device__ __forceinline__ void scatter_pk(u16* dst, const u32* src, int q, int n) {
#pragma unroll
  for (int t = 0; t < 4; ++t) {
    const int kk = (t & 1) * 2 + (n >> 3);
    u16* base = dst + (t >> 1) * 512 + (n & 7);
#pragma unroll
    for (int half = 0; half < 2; ++half) {
      const u32 v = src[2 * t + half];
      base[(4 * q + 2 * half + 0 + 16 * kk) * 8] = (u16)v;
      base[(4 * q + 2 * half + 1 + 16 * kk) * 8] = (u16)(v >> 16);
    }
  }
}

// aP dedup scatter (8 rows) WITH b61 pre-fold: stores aP + b61 (bf16-rounded).
__device__ __forceinline__ void scatter_aP(u16* dst, const floatx4* acc, int q, int n,
                                           const float* cb61) {
#pragma unroll
  for (int t = 0; t < 4; ++t) {
    const int kk = (t & 1) * 2 + (n >> 3);
    u16* base = dst + (t >> 1) * 256 + (n & 7);
    const float bv = cb61[16 * t + n];
    const u32 v = pk2(acc[t][0] + bv, acc[t][2] + bv);   // rows d=2q,2q+1
    base[(2 * q + 0 + 8 * kk) * 8] = (u16)v;
    base[(2 * q + 1 + 8 * kk) * 8] = (u16)(v >> 16);
  }
}

__device__ __forceinline__ void init_accL(floatx4* acc, const float* cb, int n) {
#pragma unroll
  for (int t = 0; t < 4; ++t) {
    const float b = cb[16 * t + n];
    floatx4 v; v[0] = b; v[1] = b; v[2] = b; v[3] = b;
    acc[t] = v;
  }
}

struct frag2 { short8_t f0, f1; };

__device__ __forceinline__ frag2 make_a(float apv, int q, const float* sc) {
  frag2 r;
#pragma unroll
  for (int h = 0; h < 2; ++h) {
    const int fb = 32 * h + 8 * q;
    const float4 wa0 = *(const float4*)(sc + CWPA + fb);
    const float4 wa1 = *(const float4*)(sc + CWPA + fb + 4);
    const float4 ba0 = *(const float4*)(sc + CBPA + fb);
    const float4 ba1 = *(const float4*)(sc + CBPA + fb + 4);
    uint4 pa;
    pa.x = pk2(fmaxf(fmaf(apv, wa0.x, ba0.x), 0.f), fmaxf(fmaf(apv, wa0.y, ba0.y), 0.f));
    pa.y = pk2(fmaxf(fmaf(apv, wa0.z, ba0.z), 0.f), fmaxf(fmaf(apv, wa0.w, ba0.w), 0.f));
    pa.z = pk2(fmaxf(fmaf(apv, wa1.x, ba1.x), 0.f), fmaxf(fmaf(apv, wa1.y, ba1.y), 0.f));
    pa.w = pk2(fmaxf(fmaf(apv, wa1.z, ba1.z), 0.f), fmaxf(fmaf(apv, wa1.w, ba1.w), 0.f));
    if (h == 0) r.f0 = __builtin_bit_cast(short8_t, pa);
    else        r.f1 = __builtin_bit_cast(short8_t, pa);
  }
  return r;
}

#define NBLK 256
#define NWAVE 8
#define PPW  4   // 256 blk * 8 waves * 4 pairs = 8192 pairs = 16384 graphs

__global__ __launch_bounds__(512)
__attribute__((amdgpu_waves_per_eu(2)))
void hetgnn_mfma(Params p) {
  __shared__ __align__(16) u16   sW[WS_U16];            // 96 KB weights
  __shared__ __align__(16) u16   sAct[NWAVE * PW_U16];  // 56 KB: 8 x (Eb|T1|eP|aPb)
  __shared__ __align__(16) float sConst[CSZ];           // 4.25 KB

  const int tid  = threadIdx.x;
  const int wave = tid >> 6;
  const int l    = tid & 63;
  const int q    = l >> 4;
  const int n    = l & 15;

  // ---- stage + swizzle weights (f32 global -> bf16 B-frag LDS), 12 frags/wave ----
  {
    const float* mats[9] = {p.w51, p.w61, p.w71, p.w52, p.w53, p.w62, p.w63, p.w72, p.w73};
    for (int i = 0; i < 12; ++i) {
      const int fi = wave * 12 + i;   // wave-uniform, 0..95
      const float* W;
      int t, h;
      if (fi < 48) { W = mats[fi >> 4]; const int loc = fi & 15; t = loc >> 2; h = loc & 3; }
      else { const int j = fi - 48; W = mats[3 + (j >> 3)]; const int loc = j & 7; t = loc >> 1; h = loc & 1; }
      const int nn = 16 * t + (l & 15);
      const int k0 = 32 * h + (l >> 4) * 8;
      float w[8];
#pragma unroll
      for (int j = 0; j < 8; ++j) w[j] = W[(k0 + j) * 64 + nn];
      uint4 o;
      o.x = pk2(w[0], w[1]); o.y = pk2(w[2], w[3]);
      o.z = pk2(w[4], w[5]); o.w = pk2(w[6], w[7]);
      *(uint4*)(sW + fi * 512 + l * 8) = o;
    }
  }
  if (tid < 64) {
    sConst[CB51 + tid] = p.b51[tid];
    sConst[CB52 + tid] = p.b52[tid];
    sConst[CB53 + tid] = p.b53[tid];
    sConst[CB61 + tid] = p.b61[tid];
    sConst[CB62 + tid] = p.b62[tid];
    sConst[CB63 + tid] = p.b63[tid];
    sConst[CB71 + tid] = p.b71[tid];
    sConst[CB72 + tid] = p.b72[tid];
    sConst[CB73 + tid] = p.b73[tid];
    sConst[CWPA + tid] = p.wpa[tid];
    sConst[CBPA + tid] = p.bpa[tid];
    sConst[CBPE + tid] = p.bpe[tid];
  }
  if (tid < 128) {
    sConst[CWPO + tid] = p.wpost[tid];
    sConst[CWPE + tid] = p.wpe[tid];
  }
  if (tid < 2) sConst[CBPO + tid] = p.bpost[tid];
  __syncthreads();

  // ---- cache the hottest weights (W62/W63: 8 uses/pair) in registers ----
  short8_t bw62[8], bw63[8];
#pragma unroll
  for (int f = 0; f < 8; ++f) {
    bw62[f] = *(const short8_t*)(sW + OFF_W62 + f * 512 + l * 8);
    bw63[f] = *(const short8_t*)(sW + OFF_W63 + f * 512 + l * 8);
  }

  u16* Eb  = sAct + wave * PW_U16;   // new-e (written by it0's final scatter only)
  u16* T1  = Eb + 1024;
  u16* eP  = Eb + 2048;
  u16* aPb = Eb + 3072;

  const int wslot = blockIdx.x * NWAVE + wave;

  for (int pi = 0; pi < PPW; ++pi) {
    const int g0 = (wslot * PPW + pi) * 2;   // 2 graphs: g0, g0+1
    if (g0 + 2 > p.gtot) break;

    // ---------------- pre-layer: a-rows and e-rows straight into registers ----------------
    const float apv = p.ap[(g0 + (n >> 3)) * 4 + ((n >> 1) & 3)];
    const frag2 A = make_a(apv, q, sConst);          // persists across both iterations
    short8_t e0, e1;
    {
      const float f0 = p.ef[(g0 + (n >> 3)) * 16 + (n & 7) * 2];
      const float f1 = p.ef[(g0 + (n >> 3)) * 16 + (n & 7) * 2 + 1];
#pragma unroll
      for (int h = 0; h < 2; ++h) {
        const int fb = 32 * h + 8 * q;
        const float4 w00 = *(const float4*)(sConst + CWPE + fb);
        const float4 w01 = *(const float4*)(sConst + CWPE + fb + 4);
        const float4 w10 = *(const float4*)(sConst + CWPE + 64 + fb);
        const float4 w11 = *(const float4*)(sConst + CWPE + 64 + fb + 4);
        const float4 be0 = *(const float4*)(sConst + CBPE + fb);
        const float4 be1 = *(const float4*)(sConst + CBPE + fb + 4);
        uint4 pe;
        pe.x = pk2(fmaxf(fmaf(f0, w00.x, fmaf(f1, w10.x, be0.x)), 0.f),
                   fmaxf(fmaf(f0, w00.y, fmaf(f1, w10.y, be0.y)), 0.f));
        pe.y = pk2(fmaxf(fmaf(f0, w00.z, fmaf(f1, w10.z, be0.z)), 0.f),
                   fmaxf(fmaf(f0, w00.w, fmaf(f1, w10.w, be0.w)), 0.f));
        pe.z = pk2(fmaxf(fmaf(f0, w01.x, fmaf(f1, w11.x, be1.x)), 0.f),
                   fmaxf(fmaf(f0, w01.y, fmaf(f1, w11.y, be1.y)), 0.f));
        pe.w = pk2(fmaxf(fmaf(f0, w01.z, fmaf(f1, w11.z, be1.z)), 0.f),
                   fmaxf(fmaf(f0, w01.w, fmaf(f1, w11.w, be1.w)), 0.f));
        if (h == 0) e0 = __builtin_bit_cast(short8_t, pe);
        else        e1 = __builtin_bit_cast(short8_t, pe);
      }
    }

    // ---- aP = a @ w61[:64] (+ b61 pre-fold): iteration-invariant ----
    {
      floatx4 accA[4];
#pragma unroll
      for (int t = 0; t < 4; ++t) { accA[t][0] = 0.f; accA[t][1] = 0.f; accA[t][2] = 0.f; accA[t][3] = 0.f; }
      layerK64R<4>(accA, A.f0, A.f1, sW + OFF_W61, l);
      scatter_aP(aPb, accA, q, n, sConst + CB61);
    }

    // ---------------- 2 shared-weight update iterations ----------------
#pragma unroll 1
    for (int it = 0; it < 2; ++it) {
      if (it == 1) { e0 = ldA(Eb, l); e1 = ldA(Eb + 512, l); }  // new e from it0

      // ---- mlp5 -> m1 (packed raw bf16; relu deferred to max) ----
      u32 m1p[8];
      {
        floatx4 acc[4]; init_accL(acc, sConst + CB51, n);
        layerK128R(acc, A.f0, A.f1, e0, e1, sW + OFF_W51, l);
        scatter_relu_bf16(T1, acc, q, n);
        floatx4 acc2[4]; init_accL(acc2, sConst + CB52, n);
        layerK64R<2>(acc2, ldA(T1, l), ldA(T1 + 512, l), sW + OFF_W52, l);
        scatter_relu_bf16(T1, acc2, q, n);
        floatx4 acc3[4]; init_accL(acc3, sConst + CB53, n);
        layerK64R<2>(acc3, ldA(T1, l), ldA(T1 + 512, l), sW + OFF_W53, l);
#pragma unroll
        for (int t = 0; t < 4; ++t) {
          m1p[2 * t + 0] = pk2(acc3[t][0], acc3[t][1]);
          m1p[2 * t + 1] = pk2(acc3[t][2], acc3[t][3]);
        }
      }

      // ---- mlp6 -> m2 (masked running max; h in regs; W62/W63 from regs) ----
      u32 m2p[8];
#pragma unroll
      for (int i = 0; i < 8; ++i) m2p[i] = 0u;
      {
        floatx4 accE[4];
#pragma unroll
        for (int t = 0; t < 4; ++t) { accE[t][0] = 0.f; accE[t][1] = 0.f; accE[t][2] = 0.f; accE[t][3] = 0.f; }
        layerK64R<4>(accE, e0, e1, sW + OFF_W61 + 2 * 512, l);
        scatter_bf16(eP, accE, q, n);

        const int d = n >> 1;
#pragma unroll 2
        for (int bp = 0; bp < 4; ++bp) {
          const int re = (n & 8) + bp * 2 + (n & 1);
          short8_t h0, h1;
#pragma unroll
          for (int h = 0; h < 2; ++h) {
            const uint4 av = *(const uint4*)(aPb + h * 256 + (d + 8 * q) * 8);
            const uint4 ev = *(const uint4*)(eP + h * 512 + (re + 16 * q) * 8);
            uint4 ph;   // b61 already folded into av
            ph.x = pk2(fmaxf(blo(av.x) + blo(ev.x), 0.f),
                       fmaxf(bhi(av.x) + bhi(ev.x), 0.f));
            ph.y = pk2(fmaxf(blo(av.y) + blo(ev.y), 0.f),
                       fmaxf(bhi(av.y) + bhi(ev.y), 0.f));
            ph.z = pk2(fmaxf(blo(av.z) + blo(ev.z), 0.f),
                       fmaxf(bhi(av.z) + bhi(ev.z), 0.f));
            ph.w = pk2(fmaxf(blo(av.w) + blo(ev.w), 0.f),
                       fmaxf(bhi(av.w) + bhi(ev.w), 0.f));
            if (h == 0) h0 = __builtin_bit_cast(short8_t, ph);
            else        h1 = __builtin_bit_cast(short8_t, ph);
          }
          floatx4 acc2[4]; init_accL(acc2, sConst + CB62, n);
          layerK64B(acc2, h0, h1, bw62);
          scatter_relu_bf16(T1, acc2, q, n);
          floatx4 acc3[4]; init_accL(acc3, sConst + CB63, n);
          layerK64B(acc3, ldA(T1, l), ldA(T1 + 512, l), bw63);
#pragma unroll
          for (int t = 0; t < 4; ++t) {
#pragma unroll
            for (int h = 0; h < 2; ++h) {
              const u32 cand = pk2(acc3[t][2 * h], acc3[t][2 * h + 1]);
              const u32 mx = pkmax(m2p[2 * t + h], cand);
              m2p[2 * t + h] = (((2 * q + h) & 3) != bp) ? mx : m2p[2 * t + h];
            }
          }
        }
      }

      // ---- agg (packed) + mlp7 ----
      {
        u32 agp[8];
#pragma unroll
        for (int i = 0; i < 8; ++i) agp[i] = pkmax(ror16(m1p[i]), m2p[i]);
        scatter_pk(T1, agp, q, n);
        floatx4 acc[4]; init_accL(acc, sConst + CB71, n);
        layerK128R(acc, ldA(T1, l), ldA(T1 + 512, l), e0, e1, sW + OFF_W71, l);
        scatter_relu_bf16(T1, acc, q, n);
        floatx4 acc2[4]; init_accL(acc2, sConst + CB72, n);
        layerK64R<2>(acc2, ldA(T1, l), ldA(T1 + 512, l), sW + OFF_W72, l);
        scatter_relu_bf16(T1, acc2, q, n);
        floatx4 acc3[4]; init_accL(acc3, sConst + CB73, n);
        layerK64R<2>(acc3, ldA(T1, l), ldA(T1 + 512, l), sW + OFF_W73, l);

        if (it == 0) {
          scatter_relu_bf16(Eb, acc3, q, n);   // new e (cross-lane -> LDS)
        } else {
          // ---- post linear + per-(g,b) L2 row normalization ----
          float prr[4] = {0.f, 0.f, 0.f, 0.f}, pii[4] = {0.f, 0.f, 0.f, 0.f};
#pragma unroll
          for (int t = 0; t < 4; ++t) {
            const float wr = sConst[CWPO + (16 * t + n) * 2];
            const float wi = sConst[CWPO + (16 * t + n) * 2 + 1];
#pragma unroll
            for (int r = 0; r < 4; ++r) {
              const float e = fmaxf(acc3[t][r], 0.f);
              prr[r] = fmaf(e, wr, prr[r]);
              pii[r] = fmaf(e, wi, pii[r]);
            }
          }
          const float bpR = sConst[CBPO], bpI = sConst[CBPO + 1];
#pragma unroll
          for (int r = 0; r < 4; ++r) {
#pragma unroll
            for (int off = 1; off < 16; off <<= 1) {
              prr[r] += __shfl_xor(prr[r], off, 16);
              pii[r] += __shfl_xor(pii[r], off, 16);
            }
            prr[r] += bpR;
            pii[r] += bpI;
          }
          const int r = n >> 1, c = n & 1, rp = r ^ 1;
          const float pr_r  = sel4(r,  prr[0], prr[1], prr[2], prr[3]);
          const float pi_r  = sel4(r,  pii[0], pii[1], pii[2], pii[3]);
          const float pr_rp = sel4(rp, prr[0], prr[1], prr[2], prr[3]);
          const float pi_rp = sel4(rp, pii[0], pii[1], pii[2], pii[3]);
          const float num = c ? pi_r : pr_r;
          const float n2  = pr_r * pr_r + pi_r * pi_r + pr_rp * pr_rp + pi_rp * pi_rp;
          if (n < 8) p.out[g0 * 16 + (4 * q + r) * 2 + c] = num / sqrtf(n2);
        }
      }
    }
  }
}

extern "C" void kernel_launch(void* const* d_in, const int* in_sizes, int n_in,
                              void* d_out, int out_size, void* d_ws, size_t ws_size,
                              hipStream_t stream) {
  Params p;
  p.ap    = (const float*)d_in[0];
  p.ef    = (const float*)d_in[1];
  p.wpa   = (const float*)d_in[2];  p.bpa   = (const float*)d_in[3];
  p.wpe   = (const float*)d_in[4];  p.bpe   = (const float*)d_in[5];
  p.w51   = (const float*)d_in[6];  p.b51   = (const float*)d_in[7];
  p.w52   = (const float*)d_in[8];  p.b52   = (const float*)d_in[9];
  p.w53   = (const float*)d_in[10]; p.b53   = (const float*)d_in[11];
  p.w61   = (const float*)d_in[12]; p.b61   = (const float*)d_in[13];
  p.w62   = (const float*)d_in[14]; p.b62   = (const float*)d_in[15];
  p.w63   = (const float*)d_in[16]; p.b63   = (const float*)d_in[17];
  p.w71   = (const float*)d_in[18]; p.b71   = (const float*)d_in[19];
  p.w72   = (const float*)d_in[20]; p.b72   = (const float*)d_in[21];
  p.w73   = (const float*)d_in[22]; p.b73   = (const float*)d_in[23];
  p.wpost = (const float*)d_in[24]; p.bpost = (const float*)d_in[25];
  p.out   = (float*)d_out;
  p.gtot  = in_sizes[0] / 4;  // G from ap_feat [G,B,1]

  hipLaunchKernelGGL(hetgnn_mfma, dim3(NBLK), dim3(512), 0, stream, p);
}

// Round 14
// 166.308 us; speedup vs baseline: 1.2116x; 1.0526x over previous
//
#include <hip/hip_runtime.h>

// HetGNN fused kernel, round 14: drop the dead diagonal of mlp6.
// Reference computes M2[g,b,bp,k] for all 16 (b,bp) pairs, masked-max discards
// bp==b. R13 mirrored that (4 bp-tiles, 16 dead rows of 64). Repack as 3
// neighbor-tiles: tile j holds for each (g,b,k) row its j-th neighbor
// bp_j(b) = j + (j>=b); every tile has the standard 16-row layout, so
// m2 = pkmax over 3 tiles -- exclusion predicate gone, diagonal never
// computed. mlp6 64->48 rows: -16 MFMA, -1 scatter/gather/h-build per
// pair-iter. Exact: candidate set identical; negative int16-pkmax
// intermediates can't survive the final pkmax-with-0 (deferred relu).

typedef unsigned short u16;
typedef unsigned int   u32;
typedef __attribute__((ext_vector_type(8))) short short8_t;
typedef __attribute__((ext_vector_type(2))) short short2v;
typedef __attribute__((ext_vector_type(4))) float floatx4;

// u16 offsets of each matrix's fragment block inside sW (fi*512 ordering).
#define OFF_W51 0
#define OFF_W61 8192
#define OFF_W71 16384
#define OFF_W52 24576
#define OFF_W53 28672
#define OFF_W62 32768
#define OFF_W63 36864
#define OFF_W72 40960
#define OFF_W73 45056
#define WS_U16  49152

// f32 offsets inside the sConst LDS table.
#define CB51 0
#define CB52 64
#define CB53 128
#define CB61 192
#define CB62 256
#define CB63 320
#define CB71 384
#define CB72 448
#define CB73 512
#define CWPO 576
#define CBPO 704
#define CWPA 768
#define CBPA 832
#define CWPE 896
#define CBPE 1024
#define CSZ  1088

#define PW_U16 3584   // per-wave LDS: Eb 1024 | T1 1024 | eP 1024 | aPb 512

struct Params {
  const float *ap, *ef;
  const float *wpa, *bpa, *wpe, *bpe;
  const float *w51, *b51, *w52, *b52, *w53, *b53;
  const float *w61, *b61, *w62, *b62, *w63, *b63;
  const float *w71, *b71, *w72, *b72, *w73, *b73;
  const float *wpost, *bpost;
  float *out;
  int gtot;
};

// Pack two f32 to bf16 pair: round-half-up via +0x8000, then one byte-perm.
__device__ __forceinline__ u32 pk2(float a, float b) {
  const u32 ua = __float_as_uint(a) + 0x8000u;
  const u32 ub = __float_as_uint(b) + 0x8000u;
  return __builtin_amdgcn_perm(ub, ua, 0x07060302u);  // {ub[31:16], ua[31:16]}
}
__device__ __forceinline__ float blo(u32 v) { return __uint_as_float(v << 16); }
__device__ __forceinline__ float bhi(u32 v) { return __uint_as_float(v & 0xffff0000u); }
// packed int16 max: exact bf16-max in our use because the final max-with-0
// (deferred relu) dominates any mis-ordered negative intermediate.
__device__ __forceinline__ u32 pkmax(u32 a, u32 b) {
  const short2v r = __builtin_elementwise_max(__builtin_bit_cast(short2v, a),
                                              __builtin_bit_cast(short2v, b));
  return __builtin_bit_cast(u32, r);
}
__device__ __forceinline__ u32 ror16(u32 x) { return (x >> 16) | (x << 16); }
__device__ __forceinline__ float sel4(int i, float x0, float x1, float x2, float x3) {
  const float lo = (i & 1) ? x1 : x0;
  const float hi = (i & 1) ? x3 : x2;
  return (i & 2) ? hi : lo;
}

__device__ __forceinline__ floatx4 mfma16(short8_t a, short8_t b, floatx4 c) {
  return __builtin_amdgcn_mfma_f32_16x16x32_bf16(a, b, c, 0, 0, 0);
}
__device__ __forceinline__ short8_t ldA(const u16* buf, int l) {
  return *(const short8_t*)(buf + l * 8);
}

template<int TSTRIDE>
__device__ __forceinline__ void layerK64R(floatx4* acc, short8_t a0, short8_t a1,
                                          const u16* B, int l) {
#pragma unroll
  for (int t = 0; t < 4; ++t) {
    const short8_t b0 = *(const short8_t*)(B + (t * TSTRIDE + 0) * 512 + l * 8);
    const short8_t b1 = *(const short8_t*)(B + (t * TSTRIDE + 1) * 512 + l * 8);
    acc[t] = mfma16(a0, b0, acc[t]);
    acc[t] = mfma16(a1, b1, acc[t]);
  }
}

// K=64 layer with B-frags from REGISTERS (no LDS traffic).
__device__ __forceinline__ void layerK64B(floatx4* acc, short8_t a0, short8_t a1,
                                          const short8_t* Bw) {
#pragma unroll
  for (int t = 0; t < 4; ++t) {
    acc[t] = mfma16(a0, Bw[2 * t + 0], acc[t]);
    acc[t] = mfma16(a1, Bw[2 * t + 1], acc[t]);
  }
}

__device__ __forceinline__ void layerK128R(floatx4* acc, short8_t a0, short8_t a1,
                                           short8_t a2, short8_t a3,
                                           const u16* B, int l) {
  short8_t a[4] = {a0, a1, a2, a3};
#pragma unroll
  for (int t = 0; t < 4; ++t)
#pragma unroll
    for (int h = 0; h < 4; ++h)
      acc[t] = mfma16(a[h], *(const short8_t*)(B + (t * 4 + h) * 512 + l * 8), acc[t]);
}

// C-layout regs -> A-frag-swizzled bf16 LDS (with relu). Element (m=4q+r, f=16t+n).
__device__ __forceinline__ void scatter_relu_bf16(u16* dst, const floatx4* acc, int q, int n) {
#pragma unroll
  for (int t = 0; t < 4; ++t) {
    const int kk = (t & 1) * 2 + (n >> 3);
    u16* base = dst + (t >> 1) * 512 + (n & 7);
    const u32 v01 = pk2(fmaxf(acc[t][0], 0.f), fmaxf(acc[t][1], 0.f));
    const u32 v23 = pk2(fmaxf(acc[t][2], 0.f), fmaxf(acc[t][3], 0.f));
    base[(4 * q + 0 + 16 * kk) * 8] = (u16)v01;
    base[(4 * q + 1 + 16 * kk) * 8] = (u16)(v01 >> 16);
    base[(4 * q + 2 + 16 * kk) * 8] = (u16)v23;
    base[(4 * q + 3 + 16 * kk) * 8] = (u16)(v23 >> 16);
  }
}

// Same, no relu (eP can be negative).
__device__ __forceinline__ void scatter_bf16(u16* dst, const floatx4* acc, int q, int n) {
#pragma unroll
  for (int t = 0; t < 4; ++t) {
    const int kk = (t & 1) * 2 + (n >> 3);
    u16* base = dst + (t >> 1) * 512 + (n & 7);
    const u32 v01 = pk2(acc[t][0], acc[t][1]);
    const u32 v23 = pk2(acc[t][2], acc[t][3]);
    base[(4 * q + 0 + 16 * kk) * 8] = (u16)v01;
    base[(4 * q + 1 + 16 * kk) * 8] = (u16)(v01 >> 16);
    base[(4 * q + 2 + 16 * kk) * 8] = (u16)v23;
    base[(4 * q + 3 + 16 * kk) * 8] = (u16)(v23 >> 16);
  }
}

// Packed src: src[2t+half] holds rows (4q+2half, 4q+2half+1).
__device__ __forceinline__ void scatter_pk(u16* dst, const u32* src, int q, int n) {
#pragma unroll
  for (int t = 0; t < 4; ++t) {
    const int kk = (t & 1) * 2 + (n >> 3);
    u16* base = dst + (t >> 1) * 512 + (n & 7);
#pragma unroll
    for (int half = 0; half < 2; ++half) {
      const u32 v = src[2 * t + half];
      base[(4 * q + 2 * half + 0 + 16 * kk) * 8] = (u16)v;
      base[(4 * q + 2 * half + 1 + 16 * kk) * 8] = (u16)(v >> 16);
    }
  }
}

// aP dedup scatter (8 rows) WITH b61 pre-fold: stores aP + b61 (bf16-rounded).
__device__ __forceinline__ void scatter_aP(u16* dst, const floatx4* acc, int q, int n,
                                           const float* cb61) {
#pragma unroll
  for (int t = 0; t < 4; ++t) {
    const int kk = (t & 1) * 2 + (n >> 3);
    u16* base = dst + (t >> 1) * 256 + (n & 7);
    const float bv = cb61[16 * t + n];
    const u32 v = pk2(acc[t][0] + bv, acc[t][2] + bv);   // rows d=2q,2q+1
    base[(2 * q + 0 + 8 * kk) * 8] = (u16)v;
    base[(2 * q + 1 + 8 * kk) * 8] = (u16)(v >> 16);
  }
}

__device__ __forceinline__ void init_accL(floatx4* acc, const float* cb, int n) {
#pragma unroll
  for (int t = 0; t < 4; ++t) {
    const float b = cb[16 * t + n];
    floatx4 v; v[0] = b; v[1] = b; v[2] = b; v[3] = b;
    acc[t] = v;
  }
}

struct frag2 { short8_t f0, f1; };

__device__ __forceinline__ frag2 make_a(float apv, int q, const float* sc) {
  frag2 r;
#pragma unroll
  for (int h = 0; h < 2; ++h) {
    const int fb = 32 * h + 8 * q;
    const float4 wa0 = *(const float4*)(sc + CWPA + fb);
    const float4 wa1 = *(const float4*)(sc + CWPA + fb + 4);
    const float4 ba0 = *(const float4*)(sc + CBPA + fb);
    const float4 ba1 = *(const float4*)(sc + CBPA + fb + 4);
    uint4 pa;
    pa.x = pk2(fmaxf(fmaf(apv, wa0.x, ba0.x), 0.f), fmaxf(fmaf(apv, wa0.y, ba0.y), 0.f));
    pa.y = pk2(fmaxf(fmaf(apv, wa0.z, ba0.z), 0.f), fmaxf(fmaf(apv, wa0.w, ba0.w), 0.f));
    pa.z = pk2(fmaxf(fmaf(apv, wa1.x, ba1.x), 0.f), fmaxf(fmaf(apv, wa1.y, ba1.y), 0.f));
    pa.w = pk2(fmaxf(fmaf(apv, wa1.z, ba1.z), 0.f), fmaxf(fmaf(apv, wa1.w, ba1.w), 0.f));
    if (h == 0) r.f0 = __builtin_bit_cast(short8_t, pa);
    else        r.f1 = __builtin_bit_cast(short8_t, pa);
  }
  return r;
}

#define NBLK 256
#define NWAVE 8
#define PPW  4   // 256 blk * 8 waves * 4 pairs = 8192 pairs = 16384 graphs

__global__ __launch_bounds__(512)
__attribute__((amdgpu_waves_per_eu(2)))
void hetgnn_mfma(Params p) {
  __shared__ __align__(16) u16   sW[WS_U16];            // 96 KB weights
  __shared__ __align__(16) u16   sAct[NWAVE * PW_U16];  // 56 KB: 8 x (Eb|T1|eP|aPb)
  __shared__ __align__(16) float sConst[CSZ];           // 4.25 KB

  const int tid  = threadIdx.x;
  const int wave = tid >> 6;
  const int l    = tid & 63;
  const int q    = l >> 4;
  const int n    = l & 15;

  // ---- stage + swizzle weights (f32 global -> bf16 B-frag LDS), 12 frags/wave ----
  {
    const float* mats[9] = {p.w51, p.w61, p.w71, p.w52, p.w53, p.w62, p.w63, p.w72, p.w73};
    for (int i = 0; i < 12; ++i) {
      const int fi = wave * 12 + i;   // wave-uniform, 0..95
      const float* W;
      int t, h;
      if (fi < 48) { W = mats[fi >> 4]; const int loc = fi & 15; t = loc >> 2; h = loc & 3; }
      else { const int j = fi - 48; W = mats[3 + (j >> 3)]; const int loc = j & 7; t = loc >> 1; h = loc & 1; }
      const int nn = 16 * t + (l & 15);
      const int k0 = 32 * h + (l >> 4) * 8;
      float w[8];
#pragma unroll
      for (int j = 0; j < 8; ++j) w[j] = W[(k0 + j) * 64 + nn];
      uint4 o;
      o.x = pk2(w[0], w[1]); o.y = pk2(w[2], w[3]);
      o.z = pk2(w[4], w[5]); o.w = pk2(w[6], w[7]);
      *(uint4*)(sW + fi * 512 + l * 8) = o;
    }
  }
  if (tid < 64) {
    sConst[CB51 + tid] = p.b51[tid];
    sConst[CB52 + tid] = p.b52[tid];
    sConst[CB53 + tid] = p.b53[tid];
    sConst[CB61 + tid] = p.b61[tid];
    sConst[CB62 + tid] = p.b62[tid];
    sConst[CB63 + tid] = p.b63[tid];
    sConst[CB71 + tid] = p.b71[tid];
    sConst[CB72 + tid] = p.b72[tid];
    sConst[CB73 + tid] = p.b73[tid];
    sConst[CWPA + tid] = p.wpa[tid];
    sConst[CBPA + tid] = p.bpa[tid];
    sConst[CBPE + tid] = p.bpe[tid];
  }
  if (tid < 128) {
    sConst[CWPO + tid] = p.wpost[tid];
    sConst[CWPE + tid] = p.wpe[tid];
  }
  if (tid < 2) sConst[CBPO + tid] = p.bpost[tid];
  __syncthreads();

  // ---- cache the hottest weights (W62/W63: used every bp-tile) in registers ----
  short8_t bw62[8], bw63[8];
#pragma unroll
  for (int f = 0; f < 8; ++f) {
    bw62[f] = *(const short8_t*)(sW + OFF_W62 + f * 512 + l * 8);
    bw63[f] = *(const short8_t*)(sW + OFF_W63 + f * 512 + l * 8);
  }

  u16* Eb  = sAct + wave * PW_U16;   // new-e (written by it0's final scatter only)
  u16* T1  = Eb + 1024;
  u16* eP  = Eb + 2048;
  u16* aPb = Eb + 3072;

  const int wslot = blockIdx.x * NWAVE + wave;

  for (int pi = 0; pi < PPW; ++pi) {
    const int g0 = (wslot * PPW + pi) * 2;   // 2 graphs: g0, g0+1
    if (g0 + 2 > p.gtot) break;

    // ---------------- pre-layer: a-rows and e-rows straight into registers ----------------
    const float apv = p.ap[(g0 + (n >> 3)) * 4 + ((n >> 1) & 3)];
    const frag2 A = make_a(apv, q, sConst);          // persists across both iterations
    short8_t e0, e1;
    {
      const float f0 = p.ef[(g0 + (n >> 3)) * 16 + (n & 7) * 2];
      const float f1 = p.ef[(g0 + (n >> 3)) * 16 + (n & 7) * 2 + 1];
#pragma unroll
      for (int h = 0; h < 2; ++h) {
        const int fb = 32 * h + 8 * q;
        const float4 w00 = *(const float4*)(sConst + CWPE + fb);
        const float4 w01 = *(const float4*)(sConst + CWPE + fb + 4);
        const float4 w10 = *(const float4*)(sConst + CWPE + 64 + fb);
        const float4 w11 = *(const float4*)(sConst + CWPE + 64 + fb + 4);
        const float4 be0 = *(const float4*)(sConst + CBPE + fb);
        const float4 be1 = *(const float4*)(sConst + CBPE + fb + 4);
        uint4 pe;
        pe.x = pk2(fmaxf(fmaf(f0, w00.x, fmaf(f1, w10.x, be0.x)), 0.f),
                   fmaxf(fmaf(f0, w00.y, fmaf(f1, w10.y, be0.y)), 0.f));
        pe.y = pk2(fmaxf(fmaf(f0, w00.z, fmaf(f1, w10.z, be0.z)), 0.f),
                   fmaxf(fmaf(f0, w00.w, fmaf(f1, w10.w, be0.w)), 0.f));
        pe.z = pk2(fmaxf(fmaf(f0, w01.x, fmaf(f1, w11.x, be1.x)), 0.f),
                   fmaxf(fmaf(f0, w01.y, fmaf(f1, w11.y, be1.y)), 0.f));
        pe.w = pk2(fmaxf(fmaf(f0, w01.z, fmaf(f1, w11.z, be1.z)), 0.f),
                   fmaxf(fmaf(f0, w01.w, fmaf(f1, w11.w, be1.w)), 0.f));
        if (h == 0) e0 = __builtin_bit_cast(short8_t, pe);
        else        e1 = __builtin_bit_cast(short8_t, pe);
      }
    }

    // ---- aP = a @ w61[:64] (+ b61 pre-fold): iteration-invariant ----
    {
      floatx4 accA[4];
#pragma unroll
      for (int t = 0; t < 4; ++t) { accA[t][0] = 0.f; accA[t][1] = 0.f; accA[t][2] = 0.f; accA[t][3] = 0.f; }
      layerK64R<4>(accA, A.f0, A.f1, sW + OFF_W61, l);
      scatter_aP(aPb, accA, q, n, sConst + CB61);
    }

    // ---------------- 2 shared-weight update iterations ----------------
#pragma unroll 1
    for (int it = 0; it < 2; ++it) {
      if (it == 1) { e0 = ldA(Eb, l); e1 = ldA(Eb + 512, l); }  // new e from it0

      // ---- mlp5 -> m1 (packed raw bf16; relu deferred to agg max) ----
      u32 m1p[8];
      {
        floatx4 acc[4]; init_accL(acc, sConst + CB51, n);
        layerK128R(acc, A.f0, A.f1, e0, e1, sW + OFF_W51, l);
        scatter_relu_bf16(T1, acc, q, n);
        floatx4 acc2[4]; init_accL(acc2, sConst + CB52, n);
        layerK64R<2>(acc2, ldA(T1, l), ldA(T1 + 512, l), sW + OFF_W52, l);
        scatter_relu_bf16(T1, acc2, q, n);
        floatx4 acc3[4]; init_accL(acc3, sConst + CB53, n);
        layerK64R<2>(acc3, ldA(T1, l), ldA(T1 + 512, l), sW + OFF_W53, l);
#pragma unroll
        for (int t = 0; t < 4; ++t) {
          m1p[2 * t + 0] = pk2(acc3[t][0], acc3[t][1]);
          m1p[2 * t + 1] = pk2(acc3[t][2], acc3[t][3]);
        }
      }

      // ---- mlp6 -> m2: 3 neighbor-tiles, no diagonal, no predicate ----
      u32 m2p[8];
      {
        floatx4 accE[4];
#pragma unroll
        for (int t = 0; t < 4; ++t) { accE[t][0] = 0.f; accE[t][1] = 0.f; accE[t][2] = 0.f; accE[t][3] = 0.f; }
        layerK64R<4>(accE, e0, e1, sW + OFF_W61 + 2 * 512, l);
        scatter_bf16(eP, accE, q, n);

        const int d = n >> 1;            // aPb dedup row for this lane's h-row
        const int b_ln = (n >> 1) & 3;   // batch index of this lane's h-row
#pragma unroll
        for (int j = 0; j < 3; ++j) {
          const int bp = (j >= b_ln) ? (j + 1) : j;   // j-th neighbor of b_ln
          const int re = (n & 8) + bp * 2 + (n & 1);
          short8_t h0, h1;
#pragma unroll
          for (int h = 0; h < 2; ++h) {
            const uint4 av = *(const uint4*)(aPb + h * 256 + (d + 8 * q) * 8);
            const uint4 ev = *(const uint4*)(eP + h * 512 + (re + 16 * q) * 8);
            uint4 ph;   // b61 already folded into av
            ph.x = pk2(fmaxf(blo(av.x) + blo(ev.x), 0.f),
                       fmaxf(bhi(av.x) + bhi(ev.x), 0.f));
            ph.y = pk2(fmaxf(blo(av.y) + blo(ev.y), 0.f),
                       fmaxf(bhi(av.y) + bhi(ev.y), 0.f));
            ph.z = pk2(fmaxf(blo(av.z) + blo(ev.z), 0.f),
                       fmaxf(bhi(av.z) + bhi(ev.z), 0.f));
            ph.w = pk2(fmaxf(blo(av.w) + blo(ev.w), 0.f),
                       fmaxf(bhi(av.w) + bhi(ev.w), 0.f));
            if (h == 0) h0 = __builtin_bit_cast(short8_t, ph);
            else        h1 = __builtin_bit_cast(short8_t, ph);
          }
          floatx4 acc2[4]; init_accL(acc2, sConst + CB62, n);
          layerK64B(acc2, h0, h1, bw62);
          scatter_relu_bf16(T1, acc2, q, n);
          floatx4 acc3[4]; init_accL(acc3, sConst + CB63, n);
          layerK64B(acc3, ldA(T1, l), ldA(T1 + 512, l), bw63);
#pragma unroll
          for (int t = 0; t < 4; ++t) {
#pragma unroll
            for (int h = 0; h < 2; ++h) {
              const u32 cand = pk2(acc3[t][2 * h], acc3[t][2 * h + 1]);
              m2p[2 * t + h] = (j == 0) ? cand : pkmax(m2p[2 * t + h], cand);
            }
          }
        }
      }

      // ---- agg = relu(max(m1[r^1], m2)) via pkmax-with-0, + mlp7 ----
      {
        u32 agp[8];
#pragma unroll
        for (int i = 0; i < 8; ++i)
          agp[i] = pkmax(pkmax(ror16(m1p[i]), m2p[i]), 0u);
        scatter_pk(T1, agp, q, n);
        floatx4 acc[4]; init_accL(acc, sConst + CB71, n);
        layerK128R(acc, ldA(T1, l), ldA(T1 + 512, l), e0, e1, sW + OFF_W71, l);
        scatter_relu_bf16(T1, acc, q, n);
        floatx4 acc2[4]; init_accL(acc2, sConst + CB72, n);
        layerK64R<2>(acc2, ldA(T1, l), ldA(T1 + 512, l), sW + OFF_W72, l);
        scatter_relu_bf16(T1, acc2, q, n);
        floatx4 acc3[4]; init_accL(acc3, sConst + CB73, n);
        layerK64R<2>(acc3, ldA(T1, l), ldA(T1 + 512, l), sW + OFF_W73, l);

        if (it == 0) {
          scatter_relu_bf16(Eb, acc3, q, n);   // new e (cross-lane -> LDS)
        } else {
          // ---- post linear + per-(g,b) L2 row normalization ----
          float prr[4] = {0.f, 0.f, 0.f, 0.f}, pii[4] = {0.f, 0.f, 0.f, 0.f};
#pragma unroll
          for (int t = 0; t < 4; ++t) {
            const float wr = sConst[CWPO + (16 * t + n) * 2];
            const float wi = sConst[CWPO + (16 * t + n) * 2 + 1];
#pragma unroll
            for (int r = 0; r < 4; ++r) {
              const float e = fmaxf(acc3[t][r], 0.f);
              prr[r] = fmaf(e, wr, prr[r]);
              pii[r] = fmaf(e, wi, pii[r]);
            }
          }
          const float bpR = sConst[CBPO], bpI = sConst[CBPO + 1];
#pragma unroll
          for (int r = 0; r < 4; ++r) {
#pragma unroll
            for (int off = 1; off < 16; off <<= 1) {
              prr[r] += __shfl_xor(prr[r], off, 16);
              pii[r] += __shfl_xor(pii[r], off, 16);
            }
            prr[r] += bpR;
            pii[r] += bpI;
          }
          const int r = n >> 1, c = n & 1, rp = r ^ 1;
          const float pr_r  = sel4(r,  prr[0], prr[1], prr[2], prr[3]);
          const float pi_r  = sel4(r,  pii[0], pii[1], pii[2], pii[3]);
          const float pr_rp = sel4(rp, prr[0], prr[1], prr[2], prr[3]);
          const float pi_rp = sel4(rp, pii[0], pii[1], pii[2], pii[3]);
          const float num = c ? pi_r : pr_r;
          const float n2  = pr_r * pr_r + pi_r * pi_r + pr_rp * pr_rp + pi_rp * pi_rp;
          if (n < 8) p.out[g0 * 16 + (4 * q + r) * 2 + c] = num / sqrtf(n2);
        }
      }
    }
  }
}

extern "C" void kernel_launch(void* const* d_in, const int* in_sizes, int n_in,
                              void* d_out, int out_size, void* d_ws, size_t ws_size,
                              hipStream_t stream) {
  Params p;
  p.ap    = (const float*)d_in[0];
  p.ef    = (const float*)d_in[1];
  p.wpa   = (const float*)d_in[2];  p.bpa   = (const float*)d_in[3];
  p.wpe   = (const float*)d_in[4];  p.bpe   = (const float*)d_in[5];
  p.w51   = (const float*)d_in[6];  p.b51   = (const float*)d_in[7];
  p.w52   = (const float*)d_in[8];  p.b52   = (const float*)d_in[9];
  p.w53   = (const float*)d_in[10]; p.b53   = (const float*)d_in[11];
  p.w61   = (const float*)d_in[12]; p.b61   = (const float*)d_in[13];
  p.w62   = (const float*)d_in[14]; p.b62   = (const float*)d_in[15];
  p.w63   = (const float*)d_in[16]; p.b63   = (const float*)d_in[17];
  p.w71   = (const float*)d_in[18]; p.b71   = (const float*)d_in[19];
  p.w72   = (const float*)d_in[20]; p.b72   = (const float*)d_in[21];
  p.w73   = (const float*)d_in[22]; p.b73   = (const float*)d_in[23];
  p.wpost = (const float*)d_in[24]; p.bpost = (const float*)d_in[25];
  p.out   = (float*)d_out;
  p.gtot  = in_sizes[0] / 4;  // G from ap_feat [G,B,1]

  hipLaunchKernelGGL(hetgnn_mfma, dim3(NBLK), dim3(512), 0, stream, p);
}